// Round 1
// baseline (1215.085 us; speedup 1.0000x reference)
//
#include <hip/hip_runtime.h>

#define BB 16
#define TT 30
#define NSEL 5
#define NCLS 10

// ---------------- skim resize: [B,T,3,64,64] -> [B,3,64,64]
// JAX antialiased triangle resize along H (1920 -> 64), W identity.
// sample_f = 30*oy + 14.5 ; w(j) = max(0, 1 - |sample_f - j|/30), normalized.
__global__ void skim_resize_kernel(const float* __restrict__ ff64, float* __restrict__ out) {
    int gid = blockIdx.x * blockDim.x + threadIdx.x;
    if (gid >= BB * 3 * 64 * 64) return;
    int ox = gid & 63;
    int oy = (gid >> 6) & 63;
    int c  = (gid >> 12) % 3;
    int b  = gid >> 12; b /= 3;
    float sample = 30.f * (float)oy + 14.5f;
    int jlo = max(0, 30 * oy - 16);
    int jhi = min(TT * 64 - 1, 30 * oy + 45);
    float acc = 0.f, wsum = 0.f;
    for (int j = jlo; j <= jhi; ++j) {
        float w = fmaxf(0.f, 1.f - fabsf(sample - (float)j) * (1.f / 30.f));
        int t = j >> 6, y = j & 63;
        float v = ff64[(((b * TT + t) * 3 + c) << 12) + (y << 6) + ox];
        acc += w * v;
        wsum += w;
    }
    out[gid] = acc / wsum;
}

// ---------------- generic 3x3 stride-2 SAME conv (pad lo=0, hi=1) + ReLU
__global__ void conv_s2_relu_naive(const float* __restrict__ in, const float* __restrict__ w,
                                   float* __restrict__ out,
                                   int Bn, int Cin, int Cout, int Hin, int Win,
                                   int Hout, int Wout) {
    int gid = blockIdx.x * blockDim.x + threadIdx.x;
    int total = Bn * Cout * Hout * Wout;
    if (gid >= total) return;
    int ox = gid % Wout; int tmp = gid / Wout;
    int oy = tmp % Hout; tmp /= Hout;
    int oc = tmp % Cout; int b = tmp / Cout;
    float acc = 0.f;
    const float* wp = w + oc * Cin * 9;
    for (int ic = 0; ic < Cin; ++ic) {
        const float* ip = in + (size_t)(b * Cin + ic) * Hin * Win;
        #pragma unroll
        for (int ky = 0; ky < 3; ++ky) {
            int iy = 2 * oy + ky;
            if (iy >= Hin) continue;
            #pragma unroll
            for (int kx = 0; kx < 3; ++kx) {
                int ix = 2 * ox + kx;
                if (ix >= Win) continue;
                acc += wp[(ic * 3 + ky) * 3 + kx] * ip[iy * Win + ix];
            }
        }
    }
    out[gid] = fmaxf(acc, 0.f);
}

// ---------------- policy: mean(h2) -> relu -> @pol_w + pol_b -> top-5 idx sorted
__global__ void policy_topk_kernel(const float* __restrict__ h2, const float* __restrict__ pol_w,
                                   const float* __restrict__ pol_b, int* __restrict__ idx_out) {
    int b = blockIdx.x;
    int t = threadIdx.x; // 64 threads
    __shared__ float fea[64];
    __shared__ float logits[TT];
    const float* hp = h2 + (size_t)(b * 64 + t) * 256;
    float s = 0.f;
    for (int i = 0; i < 256; ++i) s += hp[i];
    fea[t] = fmaxf(s * (1.f / 256.f), 0.f);
    __syncthreads();
    if (t < TT) {
        float l = pol_b[t];
        for (int c = 0; c < 64; ++c) l += fea[c] * pol_w[c * TT + t];
        logits[t] = l;
    }
    __syncthreads();
    if (t == 0) {
        int sel[NSEL];
        bool used[TT];
        for (int i = 0; i < TT; ++i) used[i] = false;
        for (int k = 0; k < NSEL; ++k) {
            int best = 0; float bv = -1e30f; bool found = false;
            for (int i = 0; i < TT; ++i)
                if (!used[i] && (!found || logits[i] > bv)) { bv = logits[i]; best = i; found = true; }
            used[best] = true; sel[k] = best;
        }
        for (int a = 0; a < NSEL; ++a)
            for (int bb2 = a + 1; bb2 < NSEL; ++bb2)
                if (sel[bb2] < sel[a]) { int tmp = sel[a]; sel[a] = sel[bb2]; sel[bb2] = tmp; }
        for (int k = 0; k < NSEL; ++k) idx_out[b * NSEL + k] = sel[k];
    }
}

// ---------------- eval gather + resize: FF224 gathered by idx -> [B,3,224,224]
// H: 1120 -> 224, sample_f = 5*oy + 2, w(j) = max(0, 1 - |sample_f - j|/5), normalized.
__global__ void eval_resize_kernel(const float* __restrict__ ff224, const int* __restrict__ idx,
                                   float* __restrict__ out) {
    int gid = blockIdx.x * blockDim.x + threadIdx.x;
    int total = BB * 3 * 224 * 224;
    if (gid >= total) return;
    int ox = gid % 224; int tmp = gid / 224;
    int oy = tmp % 224; tmp /= 224;
    int c = tmp % 3; int b = tmp / 3;
    float sample = 5.f * (float)oy + 2.f;
    int jlo = max(0, 5 * oy - 3);
    int jhi = min(NSEL * 224 - 1, 5 * oy + 7);
    float acc = 0.f, wsum = 0.f;
    for (int j = jlo; j <= jhi; ++j) {
        float w = fmaxf(0.f, 1.f - fabsf(sample - (float)j) * 0.2f);
        int s = j / 224, y = j % 224;
        int t = idx[b * NSEL + s];
        acc += w * ff224[((size_t)((b * TT + t) * 3 + c) * 224 + y) * 224 + ox];
        wsum += w;
    }
    out[gid] = acc / wsum;
}

// ---------------- eval conv2: [B,64,112,112] -> [B,128,56,56], 8 oc per thread
__global__ void conv2_eval_oc8(const float* __restrict__ in, const float* __restrict__ w,
                               float* __restrict__ out) {
    int gid = blockIdx.x * blockDim.x + threadIdx.x;
    int total = BB * 16 * 56 * 56;
    if (gid >= total) return;
    int ox = gid % 56; int tmp = gid / 56;
    int oy = tmp % 56; tmp /= 56;
    int ocg = tmp % 16; int b = tmp / 16;
    int oc0 = ocg * 8;
    float acc[8] = {0.f, 0.f, 0.f, 0.f, 0.f, 0.f, 0.f, 0.f};
    for (int ic = 0; ic < 64; ++ic) {
        const float* ip = in + (size_t)(b * 64 + ic) * 112 * 112;
        const float* wp = w + (size_t)(oc0 * 64 + ic) * 9;
        #pragma unroll
        for (int ky = 0; ky < 3; ++ky) {
            int iy = 2 * oy + ky;
            if (iy >= 112) continue;
            #pragma unroll
            for (int kx = 0; kx < 3; ++kx) {
                int ix = 2 * ox + kx;
                if (ix >= 112) continue;
                float v = ip[iy * 112 + ix];
                #pragma unroll
                for (int j = 0; j < 8; ++j)
                    acc[j] += v * wp[(size_t)j * 576 + ky * 3 + kx];
            }
        }
    }
    #pragma unroll
    for (int j = 0; j < 8; ++j)
        out[((size_t)(b * 128 + oc0 + j) * 56 + oy) * 56 + ox] = fmaxf(acc[j], 0.f);
}

// ---------------- mean over 56x56 per (b,c): one wave per channel image
__global__ void gmean_kernel(const float* __restrict__ g2, float* __restrict__ gmean) {
    int bc = blockIdx.x; // 0 .. B*128-1
    const float* p = g2 + (size_t)bc * 3136;
    float s = 0.f;
    for (int i = threadIdx.x; i < 3136; i += 64) s += p[i];
    for (int off = 32; off; off >>= 1) s += __shfl_down(s, off);
    if (threadIdx.x == 0) gmean[bc] = s * (1.f / 3136.f);
}

// ---------------- final FC: [B,128] @ [128,10] + b
__global__ void fc_kernel(const float* __restrict__ gmean, const float* __restrict__ fcw,
                          const float* __restrict__ fcb, float* __restrict__ out) {
    int gid = blockIdx.x * blockDim.x + threadIdx.x;
    if (gid >= BB * NCLS) return;
    int cls = gid % NCLS, b = gid / NCLS;
    float s = fcb[cls];
    for (int c = 0; c < 128; ++c) s += gmean[b * 128 + c] * fcw[c * NCLS + cls];
    out[gid] = s;
}

extern "C" void kernel_launch(void* const* d_in, const int* in_sizes, int n_in,
                              void* d_out, int out_size, void* d_ws, size_t ws_size,
                              hipStream_t stream) {
    const float* ff64  = (const float*)d_in[0];
    const float* ff224 = (const float*)d_in[1];
    const float* sw1   = (const float*)d_in[2];
    const float* sw2   = (const float*)d_in[3];
    const float* polw  = (const float*)d_in[4];
    const float* polb  = (const float*)d_in[5];
    const float* ew1   = (const float*)d_in[6];
    const float* ew2   = (const float*)d_in[7];
    const float* fcw   = (const float*)d_in[8];
    const float* fcb   = (const float*)d_in[9];
    float* out = (float*)d_out;

    float* ws = (float*)d_ws;
    float* skim_res = ws;                     // 196608
    float* h1 = skim_res + 196608;            // 524288
    float* h2 = h1 + 524288;                  // 262144
    int*   idx = (int*)(h2 + 262144);         // 80 ints
    float* gmean = (float*)(idx + 80);        // 2048
    float* eval_in = gmean + 2048;            // 2408448
    float* g1 = eval_in + 2408448;            // 12845056
    float* g2 = g1 + 12845056;                // 6422528

    // skim branch
    skim_resize_kernel<<<(196608 + 255) / 256, 256, 0, stream>>>(ff64, skim_res);
    conv_s2_relu_naive<<<(524288 + 255) / 256, 256, 0, stream>>>(
        skim_res, sw1, h1, BB, 3, 32, 64, 64, 32, 32);
    conv_s2_relu_naive<<<(262144 + 255) / 256, 256, 0, stream>>>(
        h1, sw2, h2, BB, 32, 64, 32, 32, 16, 16);
    policy_topk_kernel<<<BB, 64, 0, stream>>>(h2, polw, polb, idx);

    // eval branch
    eval_resize_kernel<<<(2408448 + 255) / 256, 256, 0, stream>>>(ff224, idx, eval_in);
    conv_s2_relu_naive<<<(12845056 + 255) / 256, 256, 0, stream>>>(
        eval_in, ew1, g1, BB, 3, 64, 224, 224, 112, 112);
    conv2_eval_oc8<<<(802816 + 255) / 256, 256, 0, stream>>>(g1, ew2, g2);
    gmean_kernel<<<BB * 128, 64, 0, stream>>>(g2, gmean);
    fc_kernel<<<1, 256, 0, stream>>>(gmean, fcw, fcb, out);
}

// Round 2
// 624.105 us; speedup vs baseline: 1.9469x; 1.9469x over previous
//
#include <hip/hip_runtime.h>

#define BB 16
#define TT 30
#define NSEL 5
#define NCLS 10

// ---------------- skim resize: [B,T,3,64,64] -> [B,3,64,64]
// JAX antialiased triangle resize along H (1920 -> 64), W identity.
__global__ void skim_resize_kernel(const float* __restrict__ ff64, float* __restrict__ out) {
    int gid = blockIdx.x * blockDim.x + threadIdx.x;
    if (gid >= BB * 3 * 64 * 64) return;
    int ox = gid & 63;
    int oy = (gid >> 6) & 63;
    int c  = (gid >> 12) % 3;
    int b  = gid >> 12; b /= 3;
    float sample = 30.f * (float)oy + 14.5f;
    int jlo = max(0, 30 * oy - 16);
    int jhi = min(TT * 64 - 1, 30 * oy + 45);
    float acc = 0.f, wsum = 0.f;
    for (int j = jlo; j <= jhi; ++j) {
        float w = fmaxf(0.f, 1.f - fabsf(sample - (float)j) * (1.f / 30.f));
        int t = j >> 6, y = j & 63;
        float v = ff64[(((b * TT + t) * 3 + c) << 12) + (y << 6) + ox];
        acc += w * v;
        wsum += w;
    }
    out[gid] = acc / wsum;
}

// ---------------- generic 3x3 stride-2 SAME conv (pad lo=0, hi=1) + ReLU (small skim convs)
__global__ void conv_s2_relu_naive(const float* __restrict__ in, const float* __restrict__ w,
                                   float* __restrict__ out,
                                   int Bn, int Cin, int Cout, int Hin, int Win,
                                   int Hout, int Wout) {
    int gid = blockIdx.x * blockDim.x + threadIdx.x;
    int total = Bn * Cout * Hout * Wout;
    if (gid >= total) return;
    int ox = gid % Wout; int tmp = gid / Wout;
    int oy = tmp % Hout; tmp /= Hout;
    int oc = tmp % Cout; int b = tmp / Cout;
    float acc = 0.f;
    const float* wp = w + oc * Cin * 9;
    for (int ic = 0; ic < Cin; ++ic) {
        const float* ip = in + (size_t)(b * Cin + ic) * Hin * Win;
        #pragma unroll
        for (int ky = 0; ky < 3; ++ky) {
            int iy = 2 * oy + ky;
            if (iy >= Hin) continue;
            #pragma unroll
            for (int kx = 0; kx < 3; ++kx) {
                int ix = 2 * ox + kx;
                if (ix >= Win) continue;
                acc += wp[(ic * 3 + ky) * 3 + kx] * ip[iy * Win + ix];
            }
        }
    }
    out[gid] = fmaxf(acc, 0.f);
}

// ---------------- policy: mean(h2) -> relu -> @pol_w + pol_b -> top-5 idx sorted
__global__ void policy_topk_kernel(const float* __restrict__ h2, const float* __restrict__ pol_w,
                                   const float* __restrict__ pol_b, int* __restrict__ idx_out) {
    int b = blockIdx.x;
    int t = threadIdx.x; // 64 threads
    __shared__ float fea[64];
    __shared__ float logits[TT];
    const float* hp = h2 + (size_t)(b * 64 + t) * 256;
    float s = 0.f;
    for (int i = 0; i < 256; ++i) s += hp[i];
    fea[t] = fmaxf(s * (1.f / 256.f), 0.f);
    __syncthreads();
    if (t < TT) {
        float l = pol_b[t];
        for (int c = 0; c < 64; ++c) l += fea[c] * pol_w[c * TT + t];
        logits[t] = l;
    }
    __syncthreads();
    if (t == 0) {
        int sel[NSEL];
        bool used[TT];
        for (int i = 0; i < TT; ++i) used[i] = false;
        for (int k = 0; k < NSEL; ++k) {
            int best = 0; float bv = -1e30f; bool found = false;
            for (int i = 0; i < TT; ++i)
                if (!used[i] && (!found || logits[i] > bv)) { bv = logits[i]; best = i; found = true; }
            used[best] = true; sel[k] = best;
        }
        for (int a = 0; a < NSEL; ++a)
            for (int bb2 = a + 1; bb2 < NSEL; ++bb2)
                if (sel[bb2] < sel[a]) { int tmp = sel[a]; sel[a] = sel[bb2]; sel[bb2] = tmp; }
        for (int k = 0; k < NSEL; ++k) idx_out[b * NSEL + k] = sel[k];
    }
}

// ---------------- eval gather + resize: FF224 gathered by idx -> [B,3,224,224]
__global__ void eval_resize_kernel(const float* __restrict__ ff224, const int* __restrict__ idx,
                                   float* __restrict__ out) {
    int gid = blockIdx.x * blockDim.x + threadIdx.x;
    int total = BB * 3 * 224 * 224;
    if (gid >= total) return;
    int ox = gid % 224; int tmp = gid / 224;
    int oy = tmp % 224; tmp /= 224;
    int c = tmp % 3; int b = tmp / 3;
    float sample = 5.f * (float)oy + 2.f;
    int jlo = max(0, 5 * oy - 3);
    int jhi = min(NSEL * 224 - 1, 5 * oy + 7);
    float acc = 0.f, wsum = 0.f;
    for (int j = jlo; j <= jhi; ++j) {
        float w = fmaxf(0.f, 1.f - fabsf(sample - (float)j) * 0.2f);
        int s = j / 224, y = j % 224;
        int t = idx[b * NSEL + s];
        acc += w * ff224[((size_t)((b * TT + t) * 3 + c) * 224 + y) * 224 + ox];
        wsum += w;
    }
    out[gid] = acc / wsum;
}

// ---------------- eval conv1: [B,3,224,224] -> [B,64,112,112], 4 px per thread
__global__ __launch_bounds__(256) void conv1_eval_px4(const float* __restrict__ in,
                                                      const float* __restrict__ w,
                                                      float* __restrict__ out) {
    int gid = blockIdx.x * blockDim.x + threadIdx.x;
    int total = BB * 64 * 112 * 28;
    if (gid >= total) return;
    int xg = gid % 28; int tmp = gid / 28;
    int oy = tmp % 112; tmp /= 112;
    int oc = tmp % 64; int b = tmp / 64;
    int ox0 = xg * 4;
    int ix0 = ox0 * 2;
    const float* wp = w + oc * 27;
    const float* ib = in + (size_t)b * 3 * 224 * 224;
    bool xok = (ix0 + 8) < 224;
    float acc[4] = {0.f, 0.f, 0.f, 0.f};
    #pragma unroll
    for (int ic = 0; ic < 3; ++ic) {
        #pragma unroll
        for (int ky = 0; ky < 3; ++ky) {
            int iy = 2 * oy + ky;
            if (iy >= 224) continue;  // only oy=111, ky=2
            const float* row = ib + ((size_t)ic * 224 + iy) * 224 + ix0;
            float xv[9];
            #pragma unroll
            for (int i = 0; i < 8; ++i) xv[i] = row[i];
            xv[8] = xok ? row[8] : 0.f;
            #pragma unroll
            for (int kx = 0; kx < 3; ++kx) {
                float wv = wp[(ic * 3 + ky) * 3 + kx];
                #pragma unroll
                for (int p = 0; p < 4; ++p)
                    acc[p] += wv * xv[2 * p + kx];
            }
        }
    }
    float* op = out + ((size_t)(b * 64 + oc) * 112 + oy) * 112 + ox0;
    #pragma unroll
    for (int p = 0; p < 4; ++p) op[p] = fmaxf(acc[p], 0.f);
}

// ---------------- weight pre-transpose for conv2: w[oc][ic][k] -> wT[ic][k][oc]
__global__ void transpose_w2(const float* __restrict__ w, float* __restrict__ wT) {
    int i = blockIdx.x * blockDim.x + threadIdx.x;
    if (i >= 128 * 64 * 9) return;
    int k = i % 9; int tmp = i / 9;
    int ic = tmp % 64; int oc = tmp / 64;
    wT[((size_t)ic * 9 + k) * 128 + oc] = w[i];
}

// ---------------- eval conv2 tiled: [B,64,112,112] -> [B,128,56,56]
// block = 128 thr; tile = 64 oc x 8 rows x 14 cols; thread = 8 oc x 7 px
__global__ __launch_bounds__(128) void conv2_tiled(const float* __restrict__ in,
                                                   const float* __restrict__ wT,
                                                   float* __restrict__ out) {
    int ty = blockIdx.x / 4;         // 0..6   oy0 = ty*8
    int tx = blockIdx.x % 4;         // 0..3   ox0 = tx*14
    int ocBase = blockIdx.y * 64;    // 0 or 64
    int b = blockIdx.z;
    int t = threadIdx.x;
    int ocg = t >> 4;                // 0..7
    int pid = t & 15;
    int r = pid >> 1;                // 0..7 (row)
    int cg = pid & 1;                // 0..1 (col group of 7)

    __shared__ float in_s[8][17][29];
    __shared__ float w_s[8][9][64];

    int oy0 = ty * 8, ox0 = tx * 14;
    int iy0 = oy0 * 2, ix0 = ox0 * 2;

    float acc[8][7];
    #pragma unroll
    for (int j = 0; j < 8; ++j)
        #pragma unroll
        for (int p = 0; p < 7; ++p) acc[j][p] = 0.f;

    const float* inb = in + (size_t)b * 64 * 112 * 112;

    for (int s = 0; s < 8; ++s) {
        __syncthreads();
        // stage input tile: 8 ic x 17 rows x 29 cols
        for (int i = t; i < 8 * 17 * 29; i += 128) {
            int l = i / (17 * 29);
            int rem = i - l * (17 * 29);
            int ry = rem / 29;
            int rx = rem - ry * 29;
            int iy = iy0 + ry, ix = ix0 + rx;
            float v = 0.f;
            if (iy < 112 && ix < 112)
                v = inb[(size_t)(s * 8 + l) * 112 * 112 + (size_t)iy * 112 + ix];
            in_s[l][ry][rx] = v;
        }
        // stage weights: 8 ic x 9 k x 64 oc (coalesced from wT)
        for (int i = t; i < 8 * 9 * 64; i += 128) {
            int oc = i & 63;
            int k = (i >> 6) % 9;
            int l = i / 576;
            w_s[l][k][oc] = wT[((size_t)(s * 8 + l) * 9 + k) * 128 + ocBase + oc];
        }
        __syncthreads();
        #pragma unroll
        for (int l = 0; l < 8; ++l) {
            #pragma unroll
            for (int ky = 0; ky < 3; ++ky) {
                float xv[15];
                #pragma unroll
                for (int i = 0; i < 15; ++i)
                    xv[i] = in_s[l][2 * r + ky][cg * 14 + i];
                #pragma unroll
                for (int kx = 0; kx < 3; ++kx) {
                    const float4* w4 = (const float4*)&w_s[l][ky * 3 + kx][ocg * 8];
                    float4 wa = w4[0];
                    float4 wb = w4[1];
                    #pragma unroll
                    for (int p = 0; p < 7; ++p) {
                        float v = xv[2 * p + kx];
                        acc[0][p] += v * wa.x;
                        acc[1][p] += v * wa.y;
                        acc[2][p] += v * wa.z;
                        acc[3][p] += v * wa.w;
                        acc[4][p] += v * wb.x;
                        acc[5][p] += v * wb.y;
                        acc[6][p] += v * wb.z;
                        acc[7][p] += v * wb.w;
                    }
                }
            }
        }
    }
    int oy = oy0 + r;
    #pragma unroll
    for (int j = 0; j < 8; ++j) {
        int oc = ocBase + ocg * 8 + j;
        float* op = out + ((size_t)(b * 128 + oc) * 56 + oy) * 56 + ox0 + cg * 7;
        #pragma unroll
        for (int p = 0; p < 7; ++p) op[p] = fmaxf(acc[j][p], 0.f);
    }
}

// ---------------- mean over 56x56 per (b,c)
__global__ void gmean_kernel(const float* __restrict__ g2, float* __restrict__ gmean) {
    int bc = blockIdx.x;
    const float* p = g2 + (size_t)bc * 3136;
    float s = 0.f;
    for (int i = threadIdx.x; i < 3136; i += 64) s += p[i];
    for (int off = 32; off; off >>= 1) s += __shfl_down(s, off);
    if (threadIdx.x == 0) gmean[bc] = s * (1.f / 3136.f);
}

// ---------------- final FC: [B,128] @ [128,10] + b
__global__ void fc_kernel(const float* __restrict__ gmean, const float* __restrict__ fcw,
                          const float* __restrict__ fcb, float* __restrict__ out) {
    int gid = blockIdx.x * blockDim.x + threadIdx.x;
    if (gid >= BB * NCLS) return;
    int cls = gid % NCLS, b = gid / NCLS;
    float s = fcb[cls];
    for (int c = 0; c < 128; ++c) s += gmean[b * 128 + c] * fcw[c * NCLS + cls];
    out[gid] = s;
}

extern "C" void kernel_launch(void* const* d_in, const int* in_sizes, int n_in,
                              void* d_out, int out_size, void* d_ws, size_t ws_size,
                              hipStream_t stream) {
    const float* ff64  = (const float*)d_in[0];
    const float* ff224 = (const float*)d_in[1];
    const float* sw1   = (const float*)d_in[2];
    const float* sw2   = (const float*)d_in[3];
    const float* polw  = (const float*)d_in[4];
    const float* polb  = (const float*)d_in[5];
    const float* ew1   = (const float*)d_in[6];
    const float* ew2   = (const float*)d_in[7];
    const float* fcw   = (const float*)d_in[8];
    const float* fcb   = (const float*)d_in[9];
    float* out = (float*)d_out;

    float* ws = (float*)d_ws;
    float* skim_res = ws;                     // 196608  (dead after skim conv1 -> reused for wT)
    float* h1 = skim_res + 196608;            // 524288
    float* h2 = h1 + 524288;                  // 262144
    int*   idx = (int*)(h2 + 262144);         // 80 ints
    float* gmean = (float*)(idx + 80);        // 2048
    float* eval_in = gmean + 2048;            // 2408448
    float* g1 = eval_in + 2408448;            // 12845056
    float* g2 = g1 + 12845056;                // 6422528
    float* wT = skim_res;                     // 73728 floats, reuses skim_res region

    // skim branch
    skim_resize_kernel<<<(196608 + 255) / 256, 256, 0, stream>>>(ff64, skim_res);
    conv_s2_relu_naive<<<(524288 + 255) / 256, 256, 0, stream>>>(
        skim_res, sw1, h1, BB, 3, 32, 64, 64, 32, 32);
    conv_s2_relu_naive<<<(262144 + 255) / 256, 256, 0, stream>>>(
        h1, sw2, h2, BB, 32, 64, 32, 32, 16, 16);
    policy_topk_kernel<<<BB, 64, 0, stream>>>(h2, polw, polb, idx);

    // weight transpose for conv2 (skim_res is dead now)
    transpose_w2<<<(128 * 64 * 9 + 255) / 256, 256, 0, stream>>>(ew2, wT);

    // eval branch
    eval_resize_kernel<<<(2408448 + 255) / 256, 256, 0, stream>>>(ff224, idx, eval_in);
    conv1_eval_px4<<<(BB * 64 * 112 * 28 + 255) / 256, 256, 0, stream>>>(eval_in, ew1, g1);
    {
        dim3 grid(28, 2, BB);
        conv2_tiled<<<grid, 128, 0, stream>>>(g1, wT, g2);
    }
    gmean_kernel<<<BB * 128, 64, 0, stream>>>(g2, gmean);
    fc_kernel<<<1, 256, 0, stream>>>(gmean, fcw, fcb, out);
}

// Round 3
// 386.371 us; speedup vs baseline: 3.1449x; 1.6153x over previous
//
#include <hip/hip_runtime.h>

#define BB 16
#define TT 30
#define NSEL 5
#define NCLS 10

// ---------------- skim resize: [B,T,3,64,64] -> [B,3,64,64]
__global__ void skim_resize_kernel(const float* __restrict__ ff64, float* __restrict__ out) {
    int gid = blockIdx.x * blockDim.x + threadIdx.x;
    if (gid >= BB * 3 * 64 * 64) return;
    int ox = gid & 63;
    int oy = (gid >> 6) & 63;
    int c  = (gid >> 12) % 3;
    int b  = gid >> 12; b /= 3;
    float sample = 30.f * (float)oy + 14.5f;
    int jlo = max(0, 30 * oy - 16);
    int jhi = min(TT * 64 - 1, 30 * oy + 45);
    float acc = 0.f, wsum = 0.f;
    for (int j = jlo; j <= jhi; ++j) {
        float w = fmaxf(0.f, 1.f - fabsf(sample - (float)j) * (1.f / 30.f));
        int t = j >> 6, y = j & 63;
        float v = ff64[(((b * TT + t) * 3 + c) << 12) + (y << 6) + ox];
        acc += w * v;
        wsum += w;
    }
    out[gid] = acc / wsum;
}

// ---------------- generic 3x3 stride-2 SAME conv + ReLU (small skim convs)
__global__ void conv_s2_relu_naive(const float* __restrict__ in, const float* __restrict__ w,
                                   float* __restrict__ out,
                                   int Bn, int Cin, int Cout, int Hin, int Win,
                                   int Hout, int Wout) {
    int gid = blockIdx.x * blockDim.x + threadIdx.x;
    int total = Bn * Cout * Hout * Wout;
    if (gid >= total) return;
    int ox = gid % Wout; int tmp = gid / Wout;
    int oy = tmp % Hout; tmp /= Hout;
    int oc = tmp % Cout; int b = tmp / Cout;
    float acc = 0.f;
    const float* wp = w + oc * Cin * 9;
    for (int ic = 0; ic < Cin; ++ic) {
        const float* ip = in + (size_t)(b * Cin + ic) * Hin * Win;
        #pragma unroll
        for (int ky = 0; ky < 3; ++ky) {
            int iy = 2 * oy + ky;
            if (iy >= Hin) continue;
            #pragma unroll
            for (int kx = 0; kx < 3; ++kx) {
                int ix = 2 * ox + kx;
                if (ix >= Win) continue;
                acc += wp[(ic * 3 + ky) * 3 + kx] * ip[iy * Win + ix];
            }
        }
    }
    out[gid] = fmaxf(acc, 0.f);
}

// ---------------- policy: mean(h2) -> relu -> @pol_w + pol_b -> top-5 idx sorted
__global__ void policy_topk_kernel(const float* __restrict__ h2, const float* __restrict__ pol_w,
                                   const float* __restrict__ pol_b, int* __restrict__ idx_out) {
    int b = blockIdx.x;
    int t = threadIdx.x; // 64 threads
    __shared__ float fea[64];
    __shared__ float logits[TT];
    const float* hp = h2 + (size_t)(b * 64 + t) * 256;
    float s = 0.f;
    for (int i = 0; i < 256; ++i) s += hp[i];
    fea[t] = fmaxf(s * (1.f / 256.f), 0.f);
    __syncthreads();
    if (t < TT) {
        float l = pol_b[t];
        for (int c = 0; c < 64; ++c) l += fea[c] * pol_w[c * TT + t];
        logits[t] = l;
    }
    __syncthreads();
    if (t == 0) {
        int sel[NSEL];
        bool used[TT];
        for (int i = 0; i < TT; ++i) used[i] = false;
        for (int k = 0; k < NSEL; ++k) {
            int best = 0; float bv = -1e30f; bool found = false;
            for (int i = 0; i < TT; ++i)
                if (!used[i] && (!found || logits[i] > bv)) { bv = logits[i]; best = i; found = true; }
            used[best] = true; sel[k] = best;
        }
        for (int a = 0; a < NSEL; ++a)
            for (int bb2 = a + 1; bb2 < NSEL; ++bb2)
                if (sel[bb2] < sel[a]) { int tmp = sel[a]; sel[a] = sel[bb2]; sel[bb2] = tmp; }
        for (int k = 0; k < NSEL; ++k) idx_out[b * NSEL + k] = sel[k];
    }
}

// ---------------- eval gather + resize: FF224 gathered by idx -> [B,3,224,224]
__global__ void eval_resize_kernel(const float* __restrict__ ff224, const int* __restrict__ idx,
                                   float* __restrict__ out) {
    int gid = blockIdx.x * blockDim.x + threadIdx.x;
    int total = BB * 3 * 224 * 224;
    if (gid >= total) return;
    int ox = gid % 224; int tmp = gid / 224;
    int oy = tmp % 224; tmp /= 224;
    int c = tmp % 3; int b = tmp / 3;
    float sample = 5.f * (float)oy + 2.f;
    int jlo = max(0, 5 * oy - 3);
    int jhi = min(NSEL * 224 - 1, 5 * oy + 7);
    float acc = 0.f, wsum = 0.f;
    for (int j = jlo; j <= jhi; ++j) {
        float w = fmaxf(0.f, 1.f - fabsf(sample - (float)j) * 0.2f);
        int s = j / 224, y = j % 224;
        int t = idx[b * NSEL + s];
        acc += w * ff224[((size_t)((b * TT + t) * 3 + c) * 224 + y) * 224 + ox];
        wsum += w;
    }
    out[gid] = acc / wsum;
}

// ---------------- eval conv1 tiled: [B,3,224,224] -> [B,64,112,112]
// block 256 thr; tile 64 oc x 8 rows x 28 cols; thread = 8 oc x 7 px
__global__ __launch_bounds__(256) void conv1_tiled(const float* __restrict__ in,
                                                   const float* __restrict__ w,
                                                   float* __restrict__ out) {
    int ty = blockIdx.x >> 2;        // 0..13
    int tx = blockIdx.x & 3;         // 0..3
    int b = blockIdx.y;
    int t = threadIdx.x;
    int ocg = t >> 5;                // 0..7 -> oc0 = ocg*8
    int pid = t & 31;
    int r = pid >> 2;                // 0..7
    int cg = pid & 3;                // 0..3

    __shared__ float in_s[3][17][57];
    __shared__ float w_s[27][64];

    int oy0 = ty * 8, ox0 = tx * 28;
    int iy0 = oy0 * 2, ix0 = ox0 * 2;

    const float* ib = in + (size_t)b * 3 * 224 * 224;
    // stage input 3x17x57
    for (int i = t; i < 3 * 17 * 57; i += 256) {
        int l = i / 969; int rem = i - l * 969;
        int ry = rem / 57; int rx = rem - ry * 57;
        int iy = iy0 + ry, ix = ix0 + rx;
        float v = 0.f;
        if (iy < 224 && ix < 224) v = ib[((size_t)l * 224 + iy) * 224 + ix];
        in_s[l][ry][rx] = v;
    }
    // stage weights transposed: w_s[k27][oc]
    for (int i = t; i < 27 * 64; i += 256) {
        int oc = i & 63, k = i >> 6;
        w_s[k][oc] = w[oc * 27 + k];
    }
    __syncthreads();

    float acc[8][7];
    #pragma unroll
    for (int j = 0; j < 8; ++j)
        #pragma unroll
        for (int p = 0; p < 7; ++p) acc[j][p] = 0.f;

    #pragma unroll
    for (int ic = 0; ic < 3; ++ic) {
        #pragma unroll
        for (int ky = 0; ky < 3; ++ky) {
            float xv[15];
            #pragma unroll
            for (int i = 0; i < 15; ++i) xv[i] = in_s[ic][2 * r + ky][cg * 14 + i];
            #pragma unroll
            for (int kx = 0; kx < 3; ++kx) {
                const float4 wa = *(const float4*)&w_s[ic * 9 + ky * 3 + kx][ocg * 8];
                const float4 wb = *(const float4*)&w_s[ic * 9 + ky * 3 + kx][ocg * 8 + 4];
                #pragma unroll
                for (int p = 0; p < 7; ++p) {
                    float v = xv[2 * p + kx];
                    acc[0][p] += v * wa.x;
                    acc[1][p] += v * wa.y;
                    acc[2][p] += v * wa.z;
                    acc[3][p] += v * wa.w;
                    acc[4][p] += v * wb.x;
                    acc[5][p] += v * wb.y;
                    acc[6][p] += v * wb.z;
                    acc[7][p] += v * wb.w;
                }
            }
        }
    }
    int oy = oy0 + r;
    #pragma unroll
    for (int j = 0; j < 8; ++j) {
        int oc = ocg * 8 + j;
        float* op = out + ((size_t)(b * 64 + oc) * 112 + oy) * 112 + ox0 + cg * 7;
        #pragma unroll
        for (int p = 0; p < 7; ++p) op[p] = fmaxf(acc[j][p], 0.f);
    }
}

// ---------------- prep: transpose conv2 weights + zero gsum
__global__ void prep_w2(const float* __restrict__ w, float* __restrict__ wT,
                        float* __restrict__ gsum) {
    int i = blockIdx.x * blockDim.x + threadIdx.x;
    if (i < BB * 128) gsum[i] = 0.f;
    if (i >= 128 * 64 * 9) return;
    int k = i % 9; int tmp = i / 9;
    int ic = tmp % 64; int oc = tmp / 64;
    wT[((size_t)ic * 9 + k) * 128 + oc] = w[i];
}

// ---------------- eval conv2 fused with relu+mean: [B,64,112,112] -> gsum[B,128]
// block 256 thr; tile 64 oc x 8 rows x 14 cols; thread = 4 oc x 7 px
__global__ __launch_bounds__(256) void conv2_fused(const float* __restrict__ in,
                                                   const float* __restrict__ wT,
                                                   float* __restrict__ gsum) {
    int ty = blockIdx.x >> 2;        // 0..6
    int tx = blockIdx.x & 3;         // 0..3
    int ocBase = blockIdx.y << 6;    // 0 or 64
    int b = blockIdx.z;
    int t = threadIdx.x;
    int ocg = t >> 4;                // 0..15 -> oc0 = ocg*4
    int pid = t & 15;
    int r = pid >> 1;                // 0..7
    int cg = pid & 1;                // 0..1

    __shared__ float in_s[8][17][29];
    __shared__ float w_s[8][9][64];

    int oy0 = ty * 8, ox0 = tx * 14;
    int iy0 = oy0 * 2, ix0 = ox0 * 2;

    float acc[4][7];
    #pragma unroll
    for (int j = 0; j < 4; ++j)
        #pragma unroll
        for (int p = 0; p < 7; ++p) acc[j][p] = 0.f;

    const float* inb = in + (size_t)b * 64 * 112 * 112;

    for (int s = 0; s < 8; ++s) {
        __syncthreads();
        for (int i = t; i < 8 * 17 * 29; i += 256) {
            int l = i / 493; int rem = i - l * 493;
            int ry = rem / 29; int rx = rem - ry * 29;
            int iy = iy0 + ry, ix = ix0 + rx;
            float v = 0.f;
            if (iy < 112 && ix < 112)
                v = inb[(size_t)(s * 8 + l) * 12544 + (size_t)iy * 112 + ix];
            in_s[l][ry][rx] = v;
        }
        for (int i = t; i < 8 * 9 * 64; i += 256) {
            int oc = i & 63;
            int k = (i >> 6) % 9;
            int l = i / 576;
            w_s[l][k][oc] = wT[((size_t)(s * 8 + l) * 9 + k) * 128 + ocBase + oc];
        }
        __syncthreads();
        #pragma unroll
        for (int l = 0; l < 8; ++l) {
            #pragma unroll
            for (int ky = 0; ky < 3; ++ky) {
                float xv[15];
                #pragma unroll
                for (int i = 0; i < 15; ++i)
                    xv[i] = in_s[l][2 * r + ky][cg * 14 + i];
                #pragma unroll
                for (int kx = 0; kx < 3; ++kx) {
                    const float4 wa = *(const float4*)&w_s[l][ky * 3 + kx][ocg * 4];
                    #pragma unroll
                    for (int p = 0; p < 7; ++p) {
                        float v = xv[2 * p + kx];
                        acc[0][p] += v * wa.x;
                        acc[1][p] += v * wa.y;
                        acc[2][p] += v * wa.z;
                        acc[3][p] += v * wa.w;
                    }
                }
            }
        }
    }
    // ReLU + spatial partial sum, 16-lane tree reduce, one atomic per (b,oc)
    #pragma unroll
    for (int j = 0; j < 4; ++j) {
        float ps = 0.f;
        #pragma unroll
        for (int p = 0; p < 7; ++p) ps += fmaxf(acc[j][p], 0.f);
        ps += __shfl_down(ps, 8);
        ps += __shfl_down(ps, 4);
        ps += __shfl_down(ps, 2);
        ps += __shfl_down(ps, 1);
        if (pid == 0) atomicAdd(&gsum[b * 128 + ocBase + ocg * 4 + j], ps);
    }
}

// ---------------- final FC: mean = gsum/3136 ; [B,128] @ [128,10] + b
__global__ void fc_kernel(const float* __restrict__ gsum, const float* __restrict__ fcw,
                          const float* __restrict__ fcb, float* __restrict__ out) {
    int gid = blockIdx.x * blockDim.x + threadIdx.x;
    if (gid >= BB * NCLS) return;
    int cls = gid % NCLS, b = gid / NCLS;
    float s = 0.f;
    for (int c = 0; c < 128; ++c) s += gsum[b * 128 + c] * fcw[c * NCLS + cls];
    out[gid] = fcb[cls] + s * (1.f / 3136.f);
}

extern "C" void kernel_launch(void* const* d_in, const int* in_sizes, int n_in,
                              void* d_out, int out_size, void* d_ws, size_t ws_size,
                              hipStream_t stream) {
    const float* ff64  = (const float*)d_in[0];
    const float* ff224 = (const float*)d_in[1];
    const float* sw1   = (const float*)d_in[2];
    const float* sw2   = (const float*)d_in[3];
    const float* polw  = (const float*)d_in[4];
    const float* polb  = (const float*)d_in[5];
    const float* ew1   = (const float*)d_in[6];
    const float* ew2   = (const float*)d_in[7];
    const float* fcw   = (const float*)d_in[8];
    const float* fcb   = (const float*)d_in[9];
    float* out = (float*)d_out;

    float* ws = (float*)d_ws;
    float* skim_res = ws;                     // 196608 (dead after skim conv1 -> reused for wT)
    float* h1 = skim_res + 196608;            // 524288
    float* h2 = h1 + 524288;                  // 262144
    int*   idx = (int*)(h2 + 262144);         // 80 ints
    float* gsum = (float*)(idx + 80);         // 2048
    float* eval_in = gsum + 2048;             // 2408448
    float* g1 = eval_in + 2408448;            // 12845056
    float* wT = skim_res;                     // 73728 floats, reuses skim_res region

    // skim branch
    skim_resize_kernel<<<(196608 + 255) / 256, 256, 0, stream>>>(ff64, skim_res);
    conv_s2_relu_naive<<<(524288 + 255) / 256, 256, 0, stream>>>(
        skim_res, sw1, h1, BB, 3, 32, 64, 64, 32, 32);
    conv_s2_relu_naive<<<(262144 + 255) / 256, 256, 0, stream>>>(
        h1, sw2, h2, BB, 32, 64, 32, 32, 16, 16);
    policy_topk_kernel<<<BB, 64, 0, stream>>>(h2, polw, polb, idx);

    // transpose conv2 weights + zero gsum (skim_res dead now)
    prep_w2<<<(128 * 64 * 9 + 255) / 256, 256, 0, stream>>>(ew2, wT, gsum);

    // eval branch
    eval_resize_kernel<<<(2408448 + 255) / 256, 256, 0, stream>>>(ff224, idx, eval_in);
    conv1_tiled<<<dim3(56, BB), 256, 0, stream>>>(eval_in, ew1, g1);
    conv2_fused<<<dim3(28, 2, BB), 256, 0, stream>>>(g1, wT, gsum);
    fc_kernel<<<1, 256, 0, stream>>>(gsum, fcw, fcb, out);
}

// Round 4
// 219.681 us; speedup vs baseline: 5.5311x; 1.7588x over previous
//
#include <hip/hip_runtime.h>

#define BB 16
#define TT 30
#define NSEL 5
#define NCLS 10

typedef __attribute__((ext_vector_type(8))) short short8_t;
typedef __attribute__((ext_vector_type(4))) float f32x4;

__device__ inline unsigned short f2bf(float x) {
    unsigned int u = __float_as_uint(x);
    unsigned int r = u + 0x7FFFu + ((u >> 16) & 1u);
    return (unsigned short)(r >> 16);
}

// ---------------- skim resize: [B,T,3,64,64] -> [B,3,64,64]
__global__ void skim_resize_kernel(const float* __restrict__ ff64, float* __restrict__ out) {
    int gid = blockIdx.x * blockDim.x + threadIdx.x;
    if (gid >= BB * 3 * 64 * 64) return;
    int ox = gid & 63;
    int oy = (gid >> 6) & 63;
    int c  = (gid >> 12) % 3;
    int b  = gid >> 12; b /= 3;
    float sample = 30.f * (float)oy + 14.5f;
    int jlo = max(0, 30 * oy - 16);
    int jhi = min(TT * 64 - 1, 30 * oy + 45);
    float acc = 0.f, wsum = 0.f;
    for (int j = jlo; j <= jhi; ++j) {
        float w = fmaxf(0.f, 1.f - fabsf(sample - (float)j) * (1.f / 30.f));
        int t = j >> 6, y = j & 63;
        float v = ff64[(((b * TT + t) * 3 + c) << 12) + (y << 6) + ox];
        acc += w * v;
        wsum += w;
    }
    out[gid] = acc / wsum;
}

// ---------------- generic 3x3 stride-2 SAME conv + ReLU (small skim convs)
__global__ void conv_s2_relu_naive(const float* __restrict__ in, const float* __restrict__ w,
                                   float* __restrict__ out,
                                   int Bn, int Cin, int Cout, int Hin, int Win,
                                   int Hout, int Wout) {
    int gid = blockIdx.x * blockDim.x + threadIdx.x;
    int total = Bn * Cout * Hout * Wout;
    if (gid >= total) return;
    int ox = gid % Wout; int tmp = gid / Wout;
    int oy = tmp % Hout; tmp /= Hout;
    int oc = tmp % Cout; int b = tmp / Cout;
    float acc = 0.f;
    const float* wp = w + oc * Cin * 9;
    for (int ic = 0; ic < Cin; ++ic) {
        const float* ip = in + (size_t)(b * Cin + ic) * Hin * Win;
        #pragma unroll
        for (int ky = 0; ky < 3; ++ky) {
            int iy = 2 * oy + ky;
            if (iy >= Hin) continue;
            #pragma unroll
            for (int kx = 0; kx < 3; ++kx) {
                int ix = 2 * ox + kx;
                if (ix >= Win) continue;
                acc += wp[(ic * 3 + ky) * 3 + kx] * ip[iy * Win + ix];
            }
        }
    }
    out[gid] = fmaxf(acc, 0.f);
}

// ---------------- policy: mean(h2) -> relu -> @pol_w + pol_b -> top-5 idx sorted
__global__ void policy_topk_kernel(const float* __restrict__ h2, const float* __restrict__ pol_w,
                                   const float* __restrict__ pol_b, int* __restrict__ idx_out) {
    int b = blockIdx.x;
    int t = threadIdx.x; // 64 threads
    __shared__ float fea[64];
    __shared__ float logits[TT];
    const float* hp = h2 + (size_t)(b * 64 + t) * 256;
    float s = 0.f;
    for (int i = 0; i < 256; ++i) s += hp[i];
    fea[t] = fmaxf(s * (1.f / 256.f), 0.f);
    __syncthreads();
    if (t < TT) {
        float l = pol_b[t];
        for (int c = 0; c < 64; ++c) l += fea[c] * pol_w[c * TT + t];
        logits[t] = l;
    }
    __syncthreads();
    if (t == 0) {
        int sel[NSEL];
        bool used[TT];
        for (int i = 0; i < TT; ++i) used[i] = false;
        for (int k = 0; k < NSEL; ++k) {
            int best = 0; float bv = -1e30f; bool found = false;
            for (int i = 0; i < TT; ++i)
                if (!used[i] && (!found || logits[i] > bv)) { bv = logits[i]; best = i; found = true; }
            used[best] = true; sel[k] = best;
        }
        for (int a = 0; a < NSEL; ++a)
            for (int bb2 = a + 1; bb2 < NSEL; ++bb2)
                if (sel[bb2] < sel[a]) { int tmp = sel[a]; sel[a] = sel[bb2]; sel[bb2] = tmp; }
        for (int k = 0; k < NSEL; ++k) idx_out[b * NSEL + k] = sel[k];
    }
}

// ---------------- eval gather + resize: FF224 gathered by idx -> [B,3,224,224]
__global__ void eval_resize_kernel(const float* __restrict__ ff224, const int* __restrict__ idx,
                                   float* __restrict__ out) {
    int gid = blockIdx.x * blockDim.x + threadIdx.x;
    int total = BB * 3 * 224 * 224;
    if (gid >= total) return;
    int ox = gid % 224; int tmp = gid / 224;
    int oy = tmp % 224; tmp /= 224;
    int c = tmp % 3; int b = tmp / 3;
    float sample = 5.f * (float)oy + 2.f;
    int jlo = max(0, 5 * oy - 3);
    int jhi = min(NSEL * 224 - 1, 5 * oy + 7);
    float acc = 0.f, wsum = 0.f;
    for (int j = jlo; j <= jhi; ++j) {
        float w = fmaxf(0.f, 1.f - fabsf(sample - (float)j) * 0.2f);
        int s = j / 224, y = j % 224;
        int t = idx[b * NSEL + s];
        acc += w * ff224[((size_t)((b * TT + t) * 3 + c) * 224 + y) * 224 + ox];
        wsum += w;
    }
    out[gid] = acc / wsum;
}

// ---------------- eval conv1 tiled: [B,3,224,224] -> channels-last bf16 [B,112,112,64]
__global__ __launch_bounds__(256) void conv1_tiled(const float* __restrict__ in,
                                                   const float* __restrict__ w,
                                                   unsigned short* __restrict__ outcl) {
    int ty = blockIdx.x >> 2;        // 0..13
    int tx = blockIdx.x & 3;         // 0..3
    int b = blockIdx.y;
    int t = threadIdx.x;
    int ocg = t >> 5;                // 0..7 -> oc0 = ocg*8
    int pid = t & 31;
    int r = pid >> 2;                // 0..7
    int cg = pid & 3;                // 0..3

    __shared__ float in_s[3][17][57];
    __shared__ float w_s[27][64];

    int oy0 = ty * 8, ox0 = tx * 28;
    int iy0 = oy0 * 2, ix0 = ox0 * 2;

    const float* ib = in + (size_t)b * 3 * 224 * 224;
    for (int i = t; i < 3 * 17 * 57; i += 256) {
        int l = i / 969; int rem = i - l * 969;
        int ry = rem / 57; int rx = rem - ry * 57;
        int iy = iy0 + ry, ix = ix0 + rx;
        float v = 0.f;
        if (iy < 224 && ix < 224) v = ib[((size_t)l * 224 + iy) * 224 + ix];
        in_s[l][ry][rx] = v;
    }
    for (int i = t; i < 27 * 64; i += 256) {
        int oc = i & 63, k = i >> 6;
        w_s[k][oc] = w[oc * 27 + k];
    }
    __syncthreads();

    float acc[8][7];
    #pragma unroll
    for (int j = 0; j < 8; ++j)
        #pragma unroll
        for (int p = 0; p < 7; ++p) acc[j][p] = 0.f;

    #pragma unroll
    for (int ic = 0; ic < 3; ++ic) {
        #pragma unroll
        for (int ky = 0; ky < 3; ++ky) {
            float xv[15];
            #pragma unroll
            for (int i = 0; i < 15; ++i) xv[i] = in_s[ic][2 * r + ky][cg * 14 + i];
            #pragma unroll
            for (int kx = 0; kx < 3; ++kx) {
                const float4 wa = *(const float4*)&w_s[ic * 9 + ky * 3 + kx][ocg * 8];
                const float4 wb = *(const float4*)&w_s[ic * 9 + ky * 3 + kx][ocg * 8 + 4];
                #pragma unroll
                for (int p = 0; p < 7; ++p) {
                    float v = xv[2 * p + kx];
                    acc[0][p] += v * wa.x;
                    acc[1][p] += v * wa.y;
                    acc[2][p] += v * wa.z;
                    acc[3][p] += v * wa.w;
                    acc[4][p] += v * wb.x;
                    acc[5][p] += v * wb.y;
                    acc[6][p] += v * wb.z;
                    acc[7][p] += v * wb.w;
                }
            }
        }
    }
    int oy = oy0 + r;
    int oxb = ox0 + cg * 7;
    #pragma unroll
    for (int p = 0; p < 7; ++p) {
        uint4 pk;
        unsigned int v0 = f2bf(fmaxf(acc[0][p], 0.f)) | ((unsigned int)f2bf(fmaxf(acc[1][p], 0.f)) << 16);
        unsigned int v1 = f2bf(fmaxf(acc[2][p], 0.f)) | ((unsigned int)f2bf(fmaxf(acc[3][p], 0.f)) << 16);
        unsigned int v2 = f2bf(fmaxf(acc[4][p], 0.f)) | ((unsigned int)f2bf(fmaxf(acc[5][p], 0.f)) << 16);
        unsigned int v3 = f2bf(fmaxf(acc[6][p], 0.f)) | ((unsigned int)f2bf(fmaxf(acc[7][p], 0.f)) << 16);
        pk.x = v0; pk.y = v1; pk.z = v2; pk.w = v3;
        *(uint4*)&outcl[((size_t)((b * 112 + oy) * 112) + oxb + p) * 64 + ocg * 8] = pk;
    }
}

// ---------------- prep: pack conv2 weights into per-lane MFMA A-fragments + zero gsum
// wpk[((tap*2+h)*8 + af)*64 + lane][j] = W[oc=af*16+(lane&15)][ic=h*32+(lane>>4)*8+j][ky][kx]
__global__ void prep_w2(const float* __restrict__ w, unsigned short* __restrict__ wpk,
                        float* __restrict__ gsum) {
    int i = blockIdx.x * blockDim.x + threadIdx.x;
    if (i < BB * 128) gsum[i] = 0.f;
    if (i >= 9 * 2 * 8 * 64 * 8) return;
    int j = i & 7;
    int lane = (i >> 3) & 63;
    int af = (i >> 9) & 7;
    int h = (i >> 12) & 1;
    int tap = i >> 13;
    int oc = af * 16 + (lane & 15);
    int ic = h * 32 + ((lane >> 4) << 3) + j;
    int ky = tap / 3, kx = tap % 3;
    wpk[i] = f2bf(w[((size_t)(oc * 64 + ic)) * 9 + ky * 3 + kx]);
}

// ---------------- eval conv2 via MFMA, fused relu+mean -> gsum[B,128]
// block 256 thr = 4 waves; block tile: 4 oy x 16 ox (64 px) x 128 oc (wave = 32 oc)
__global__ __launch_bounds__(256) void conv2_mfma(const unsigned short* __restrict__ g1cl,
                                                  const unsigned short* __restrict__ wpk,
                                                  float* __restrict__ gsum) {
    int oyT = blockIdx.x;            // 0..13 -> oy0 = oyT*4
    int oxT = blockIdx.y;            // 0..3  -> ox0 = oxT*16
    int b = blockIdx.z;
    int wv = threadIdx.x >> 6;       // 0..3 -> oc base wv*32
    int lane = threadIdx.x & 63;
    int col = lane & 15;
    int kq = lane >> 4;              // 0..3

    int ox = oxT * 16 + col;
    int oy0 = oyT * 4;

    f32x4 acc[2][4];
    #pragma unroll
    for (int a = 0; a < 2; ++a)
        #pragma unroll
        for (int n = 0; n < 4; ++n)
            acc[a][n] = (f32x4){0.f, 0.f, 0.f, 0.f};

    #pragma unroll
    for (int tap = 0; tap < 9; ++tap) {
        const int ky = tap / 3, kx = tap % 3;
        const int ix = 2 * ox + kx;
        #pragma unroll
        for (int h = 0; h < 2; ++h) {
            const unsigned short* wp = wpk + ((size_t)(((tap * 2 + h) * 8) + (wv << 1)) * 64 + lane) * 8;
            short8_t a0 = *(const short8_t*)wp;
            short8_t a1 = *(const short8_t*)(wp + 512);
            const int hic = h * 32 + kq * 8;
            #pragma unroll
            for (int nf = 0; nf < 4; ++nf) {
                int iy = 2 * (oy0 + nf) + ky;
                short8_t bv = {0, 0, 0, 0, 0, 0, 0, 0};
                if (iy < 112 && ix < 112)
                    bv = *(const short8_t*)(g1cl + ((size_t)((b * 112 + iy) * 112 + ix) << 6) + hic);
                acc[0][nf] = __builtin_amdgcn_mfma_f32_16x16x32_bf16(a0, bv, acc[0][nf], 0, 0, 0);
                acc[1][nf] = __builtin_amdgcn_mfma_f32_16x16x32_bf16(a1, bv, acc[1][nf], 0, 0, 0);
            }
        }
    }

    // fused relu + spatial sum: reduce over the 16 D-columns (ox), atomic per oc
    #pragma unroll
    for (int a = 0; a < 2; ++a) {
        float s0 = 0.f, s1 = 0.f, s2 = 0.f, s3 = 0.f;
        #pragma unroll
        for (int nf = 0; nf < 4; ++nf) {
            s0 += fmaxf(acc[a][nf][0], 0.f);
            s1 += fmaxf(acc[a][nf][1], 0.f);
            s2 += fmaxf(acc[a][nf][2], 0.f);
            s3 += fmaxf(acc[a][nf][3], 0.f);
        }
        #pragma unroll
        for (int off = 1; off < 16; off <<= 1) {
            s0 += __shfl_xor(s0, off);
            s1 += __shfl_xor(s1, off);
            s2 += __shfl_xor(s2, off);
            s3 += __shfl_xor(s3, off);
        }
        if (col == 0) {
            int ocb = wv * 32 + a * 16 + kq * 4;
            atomicAdd(&gsum[b * 128 + ocb + 0], s0);
            atomicAdd(&gsum[b * 128 + ocb + 1], s1);
            atomicAdd(&gsum[b * 128 + ocb + 2], s2);
            atomicAdd(&gsum[b * 128 + ocb + 3], s3);
        }
    }
}

// ---------------- final FC: mean = gsum/3136 ; [B,128] @ [128,10] + b
__global__ void fc_kernel(const float* __restrict__ gsum, const float* __restrict__ fcw,
                          const float* __restrict__ fcb, float* __restrict__ out) {
    int gid = blockIdx.x * blockDim.x + threadIdx.x;
    if (gid >= BB * NCLS) return;
    int cls = gid % NCLS, b = gid / NCLS;
    float s = 0.f;
    for (int c = 0; c < 128; ++c) s += gsum[b * 128 + c] * fcw[c * NCLS + cls];
    out[gid] = fcb[cls] + s * (1.f / 3136.f);
}

extern "C" void kernel_launch(void* const* d_in, const int* in_sizes, int n_in,
                              void* d_out, int out_size, void* d_ws, size_t ws_size,
                              hipStream_t stream) {
    const float* ff64  = (const float*)d_in[0];
    const float* ff224 = (const float*)d_in[1];
    const float* sw1   = (const float*)d_in[2];
    const float* sw2   = (const float*)d_in[3];
    const float* polw  = (const float*)d_in[4];
    const float* polb  = (const float*)d_in[5];
    const float* ew1   = (const float*)d_in[6];
    const float* ew2   = (const float*)d_in[7];
    const float* fcw   = (const float*)d_in[8];
    const float* fcb   = (const float*)d_in[9];
    float* out = (float*)d_out;

    float* ws = (float*)d_ws;
    float* skim_res = ws;                     // 196608 f
    float* h1 = skim_res + 196608;            // 524288 f
    float* h2 = h1 + 524288;                  // 262144 f
    int*   idx = (int*)(h2 + 262144);         // 80 int
    float* gsum = (float*)(idx + 80);         // 2048 f
    float* eval_in = gsum + 2048;             // 2408448 f
    unsigned short* g1cl = (unsigned short*)(eval_in + 2408448);  // 12845056 bf16
    unsigned short* wpk  = g1cl + 12845056;   // 73728 bf16

    // skim branch (exact fp32 -> identical top-k selection)
    skim_resize_kernel<<<(196608 + 255) / 256, 256, 0, stream>>>(ff64, skim_res);
    conv_s2_relu_naive<<<(524288 + 255) / 256, 256, 0, stream>>>(
        skim_res, sw1, h1, BB, 3, 32, 64, 64, 32, 32);
    conv_s2_relu_naive<<<(262144 + 255) / 256, 256, 0, stream>>>(
        h1, sw2, h2, BB, 32, 64, 32, 32, 16, 16);
    policy_topk_kernel<<<BB, 64, 0, stream>>>(h2, polw, polb, idx);

    // pack conv2 weights + zero gsum
    prep_w2<<<(9 * 2 * 8 * 64 * 8 + 255) / 256, 256, 0, stream>>>(ew2, wpk, gsum);

    // eval branch
    eval_resize_kernel<<<(2408448 + 255) / 256, 256, 0, stream>>>(ff224, idx, eval_in);
    conv1_tiled<<<dim3(56, BB), 256, 0, stream>>>(eval_in, ew1, g1cl);
    conv2_mfma<<<dim3(14, 4, BB), 256, 0, stream>>>(g1cl, wpk, gsum);
    fc_kernel<<<1, 256, 0, stream>>>(gsum, fcw, fcb, out);
}

// Round 5
// 197.182 us; speedup vs baseline: 6.1623x; 1.1141x over previous
//
#include <hip/hip_runtime.h>

#define BB 16
#define TT 30
#define NSEL 5
#define NCLS 10

typedef __attribute__((ext_vector_type(8))) short short8_t;
typedef __attribute__((ext_vector_type(4))) float f32x4;

__device__ inline unsigned short f2bf(float x) {
    unsigned int u = __float_as_uint(x);
    unsigned int r = u + 0x7FFFu + ((u >> 16) & 1u);
    return (unsigned short)(r >> 16);
}

// ---------------- skim resize: [B,T,3,64,64] -> [B,3,64,64]
__global__ void skim_resize_kernel(const float* __restrict__ ff64, float* __restrict__ out) {
    int gid = blockIdx.x * blockDim.x + threadIdx.x;
    if (gid >= BB * 3 * 64 * 64) return;
    int ox = gid & 63;
    int oy = (gid >> 6) & 63;
    int c  = (gid >> 12) % 3;
    int b  = gid >> 12; b /= 3;
    float sample = 30.f * (float)oy + 14.5f;
    int jlo = max(0, 30 * oy - 16);
    int jhi = min(TT * 64 - 1, 30 * oy + 45);
    float acc = 0.f, wsum = 0.f;
    for (int j = jlo; j <= jhi; ++j) {
        float w = fmaxf(0.f, 1.f - fabsf(sample - (float)j) * (1.f / 30.f));
        int t = j >> 6, y = j & 63;
        float v = ff64[(((b * TT + t) * 3 + c) << 12) + (y << 6) + ox];
        acc += w * v;
        wsum += w;
    }
    out[gid] = acc / wsum;
}

// ---------------- generic 3x3 stride-2 SAME conv + ReLU (small skim convs, exact fp32)
__global__ void conv_s2_relu_naive(const float* __restrict__ in, const float* __restrict__ w,
                                   float* __restrict__ out,
                                   int Bn, int Cin, int Cout, int Hin, int Win,
                                   int Hout, int Wout) {
    int gid = blockIdx.x * blockDim.x + threadIdx.x;
    int total = Bn * Cout * Hout * Wout;
    if (gid >= total) return;
    int ox = gid % Wout; int tmp = gid / Wout;
    int oy = tmp % Hout; tmp /= Hout;
    int oc = tmp % Cout; int b = tmp / Cout;
    float acc = 0.f;
    const float* wp = w + oc * Cin * 9;
    for (int ic = 0; ic < Cin; ++ic) {
        const float* ip = in + (size_t)(b * Cin + ic) * Hin * Win;
        #pragma unroll
        for (int ky = 0; ky < 3; ++ky) {
            int iy = 2 * oy + ky;
            if (iy >= Hin) continue;
            #pragma unroll
            for (int kx = 0; kx < 3; ++kx) {
                int ix = 2 * ox + kx;
                if (ix >= Win) continue;
                acc += wp[(ic * 3 + ky) * 3 + kx] * ip[iy * Win + ix];
            }
        }
    }
    out[gid] = fmaxf(acc, 0.f);
}

// ---------------- policy: mean(h2) -> relu -> @pol_w + pol_b -> top-5 idx sorted
__global__ void policy_topk_kernel(const float* __restrict__ h2, const float* __restrict__ pol_w,
                                   const float* __restrict__ pol_b, int* __restrict__ idx_out) {
    int b = blockIdx.x;
    int t = threadIdx.x; // 64 threads
    __shared__ float fea[64];
    __shared__ float logits[TT];
    const float* hp = h2 + (size_t)(b * 64 + t) * 256;
    float s = 0.f;
    for (int i = 0; i < 256; ++i) s += hp[i];
    fea[t] = fmaxf(s * (1.f / 256.f), 0.f);
    __syncthreads();
    if (t < TT) {
        float l = pol_b[t];
        for (int c = 0; c < 64; ++c) l += fea[c] * pol_w[c * TT + t];
        logits[t] = l;
    }
    __syncthreads();
    if (t == 0) {
        int sel[NSEL];
        bool used[TT];
        for (int i = 0; i < TT; ++i) used[i] = false;
        for (int k = 0; k < NSEL; ++k) {
            int best = 0; float bv = -1e30f; bool found = false;
            for (int i = 0; i < TT; ++i)
                if (!used[i] && (!found || logits[i] > bv)) { bv = logits[i]; best = i; found = true; }
            used[best] = true; sel[k] = best;
        }
        for (int a = 0; a < NSEL; ++a)
            for (int bb2 = a + 1; bb2 < NSEL; ++bb2)
                if (sel[bb2] < sel[a]) { int tmp = sel[a]; sel[a] = sel[bb2]; sel[bb2] = tmp; }
        for (int k = 0; k < NSEL; ++k) idx_out[b * NSEL + k] = sel[k];
    }
}

// ---------------- eval gather + resize: FF224 gathered by idx -> [B,3,224,224]
__global__ void eval_resize_kernel(const float* __restrict__ ff224, const int* __restrict__ idx,
                                   float* __restrict__ out) {
    int gid = blockIdx.x * blockDim.x + threadIdx.x;
    int total = BB * 3 * 224 * 224;
    if (gid >= total) return;
    int ox = gid % 224; int tmp = gid / 224;
    int oy = tmp % 224; tmp /= 224;
    int c = tmp % 3; int b = tmp / 3;
    float sample = 5.f * (float)oy + 2.f;
    int jlo = max(0, 5 * oy - 3);
    int jhi = min(NSEL * 224 - 1, 5 * oy + 7);
    float acc = 0.f, wsum = 0.f;
    for (int j = jlo; j <= jhi; ++j) {
        float w = fmaxf(0.f, 1.f - fabsf(sample - (float)j) * 0.2f);
        int s = j / 224, y = j % 224;
        int t = idx[b * NSEL + s];
        acc += w * ff224[((size_t)((b * TT + t) * 3 + c) * 224 + y) * 224 + ox];
        wsum += w;
    }
    out[gid] = acc / wsum;
}

// ---------------- prep: pack conv2 + conv1 weight fragments, zero gsum
// conv2: wpk[((tap*2+h)*8 + af)*64 + lane][j] = W2[oc=af*16+(lane&15)][ic=h*32+(lane>>4)*8+j][tap]
// conv1: wpk1[(af*64 + lane)*8 + j] = k<27 ? W1[oc=af*16+(lane&15)][k=(lane>>4)*8+j] : 0
__global__ void prep_w(const float* __restrict__ w2, const float* __restrict__ w1,
                       unsigned short* __restrict__ wpk, unsigned short* __restrict__ wpk1,
                       float* __restrict__ gsum) {
    int i = blockIdx.x * blockDim.x + threadIdx.x;
    if (i < BB * 128) gsum[i] = 0.f;
    if (i < 4 * 64 * 8) {
        int j = i & 7;
        int lane = (i >> 3) & 63;
        int af = i >> 9;
        int oc = af * 16 + (lane & 15);
        int k = ((lane >> 4) << 3) + j;
        wpk1[i] = (k < 27) ? f2bf(w1[oc * 27 + k]) : (unsigned short)0;
    }
    if (i >= 9 * 2 * 8 * 64 * 8) return;
    int j = i & 7;
    int lane = (i >> 3) & 63;
    int af = (i >> 9) & 7;
    int h = (i >> 12) & 1;
    int tap = i >> 13;
    int oc = af * 16 + (lane & 15);
    int ic = h * 32 + ((lane >> 4) << 3) + j;
    int ky = tap / 3, kx = tap % 3;
    wpk[i] = f2bf(w2[((size_t)(oc * 64 + ic)) * 9 + ky * 3 + kx]);
}

// ---------------- eval conv1 via MFMA: [B,3,224,224] fp32 -> channels-last bf16 [B,112,112,64]
// grid (7 oxT, 28 oyT, B); block 256 = 4 waves; wave = 1 oy row x 16 ox x 64 oc, K=32(27)
__global__ __launch_bounds__(256) void conv1_mfma(const float* __restrict__ in,
                                                  const unsigned short* __restrict__ wpk1,
                                                  unsigned short* __restrict__ outcl) {
    int oxT = blockIdx.x;            // 0..6
    int oyT = blockIdx.y;            // 0..27
    int b = blockIdx.z;
    int t = threadIdx.x;
    int w = t >> 6;                  // wave -> oy = oyT*4 + w
    int lane = t & 63;
    int col = lane & 15;
    int kq = lane >> 4;

    __shared__ float in_s[3][9][36];

    int iy0 = oyT * 8, ix0 = oxT * 32;
    const float* ib = in + (size_t)b * 3 * 224 * 224;
    for (int i = t; i < 3 * 9 * 36; i += 256) {
        int rx = i % 36; int tmp = i / 36;
        int ry = tmp % 9; int ic = tmp / 9;
        int iy = iy0 + ry, ix = ix0 + rx;
        float v = 0.f;
        if (iy < 224 && ix < 224 && rx < 34) v = ib[((size_t)ic * 224 + iy) * 224 + ix];
        in_s[ic][ry][rx] = v;
    }
    __syncthreads();

    // A fragments (4 x 16 oc)
    short8_t a[4];
    #pragma unroll
    for (int af = 0; af < 4; ++af)
        a[af] = *(const short8_t*)&wpk1[((af << 6) + lane) << 3];

    // B fragment: k = kq*8 + j over (ic*9 + ky*3 + kx), zero-pad k>=27
    unsigned int bw[4];
    #pragma unroll
    for (int jj = 0; jj < 4; ++jj) {
        unsigned int lo = 0, hi = 0;
        int k0 = (kq << 3) + jj * 2;
        {
            int k = k0;
            if (k < 27) {
                int ic = k / 9, r9 = k - ic * 9;
                int ky = r9 / 3, kx = r9 - ky * 3;
                lo = f2bf(in_s[ic][2 * w + ky][2 * col + kx]);
            }
        }
        {
            int k = k0 + 1;
            if (k < 27) {
                int ic = k / 9, r9 = k - ic * 9;
                int ky = r9 / 3, kx = r9 - ky * 3;
                hi = f2bf(in_s[ic][2 * w + ky][2 * col + kx]);
            }
        }
        bw[jj] = lo | (hi << 16);
    }
    short8_t bv;
    {
        unsigned int* bvp = (unsigned int*)&bv;
        bvp[0] = bw[0]; bvp[1] = bw[1]; bvp[2] = bw[2]; bvp[3] = bw[3];
    }

    f32x4 acc[4];
    #pragma unroll
    for (int af = 0; af < 4; ++af) {
        acc[af] = (f32x4){0.f, 0.f, 0.f, 0.f};
        acc[af] = __builtin_amdgcn_mfma_f32_16x16x32_bf16(a[af], bv, acc[af], 0, 0, 0);
    }

    // store: C row = oc = af*16 + kq*4 + reg ; col = px
    int oy = oyT * 4 + w;
    int ox = oxT * 16 + col;
    size_t pxb = ((size_t)((b * 112 + oy) * 112 + ox)) << 6;
    #pragma unroll
    for (int af = 0; af < 4; ++af) {
        unsigned int p0 = f2bf(fmaxf(acc[af][0], 0.f)) | ((unsigned int)f2bf(fmaxf(acc[af][1], 0.f)) << 16);
        unsigned int p1 = f2bf(fmaxf(acc[af][2], 0.f)) | ((unsigned int)f2bf(fmaxf(acc[af][3], 0.f)) << 16);
        uint2 pk; pk.x = p0; pk.y = p1;
        *(uint2*)&outcl[pxb + (af << 4) + (kq << 2)] = pk;
    }
}

// ---------------- eval conv2 via MFMA + LDS-staged input, fused relu+mean -> gsum[B,128]
// grid (14 oyT, 4 oxT, B); block 256 = 4 waves (wave = 32 oc); tile 9 rows x 34 ix x 64 ch in LDS
__global__ __launch_bounds__(256) void conv2_mfma(const unsigned short* __restrict__ g1cl,
                                                  const unsigned short* __restrict__ wpk,
                                                  float* __restrict__ gsum) {
    int oyT = blockIdx.x;            // 0..13 -> oy0 = oyT*4
    int oxT = blockIdx.y;            // 0..3  -> ox0 = oxT*16
    int b = blockIdx.z;
    int t = threadIdx.x;
    int wv = t >> 6;                 // 0..3 -> oc base wv*32
    int lane = t & 63;
    int col = lane & 15;
    int kq = lane >> 4;

    __shared__ unsigned short tile[9 * 34 * 64];

    int iy0 = oyT * 8, ix0 = oxT * 32;
    // stage 9x34 px x 64ch bf16, XOR-swizzled at 16B granularity
    for (int u = t; u < 9 * 34 * 8; u += 256) {
        int cg = u & 7;
        int r = u >> 3;              // linear px in tile = ry*34+rx
        int rx = r % 34, ry = r / 34;
        int iy = iy0 + ry, ix = ix0 + rx;
        uint4 v = {0, 0, 0, 0};
        if (iy < 112 && ix < 112)
            v = *(const uint4*)&g1cl[(((size_t)((b * 112 + iy) * 112 + ix)) << 6) + (cg << 3)];
        int byte = ((r << 6) + (cg << 3)) << 1;
        byte ^= ((r >> 1) & 7) << 4;
        *(uint4*)((char*)tile + byte) = v;
    }
    __syncthreads();

    f32x4 acc[2][4];
    #pragma unroll
    for (int a = 0; a < 2; ++a)
        #pragma unroll
        for (int n = 0; n < 4; ++n)
            acc[a][n] = (f32x4){0.f, 0.f, 0.f, 0.f};

    #pragma unroll
    for (int tap = 0; tap < 9; ++tap) {
        const int ky = tap / 3, kx = tap % 3;
        const int rx = 2 * col + kx;
        #pragma unroll
        for (int h = 0; h < 2; ++h) {
            const unsigned short* wp = wpk + ((size_t)(((tap * 2 + h) * 8) + (wv << 1)) * 64 + lane) * 8;
            short8_t a0 = *(const short8_t*)wp;
            short8_t a1 = *(const short8_t*)(wp + 512);
            const int e = (h << 5) + (kq << 3);
            #pragma unroll
            for (int nf = 0; nf < 4; ++nf) {
                int r = (2 * nf + ky) * 34 + rx;
                int byte = (((r << 6) + e) << 1) ^ (((r >> 1) & 7) << 4);
                short8_t bv = *(const short8_t*)((const char*)tile + byte);
                acc[0][nf] = __builtin_amdgcn_mfma_f32_16x16x32_bf16(a0, bv, acc[0][nf], 0, 0, 0);
                acc[1][nf] = __builtin_amdgcn_mfma_f32_16x16x32_bf16(a1, bv, acc[1][nf], 0, 0, 0);
            }
        }
    }

    // fused relu + spatial sum: reduce over the 16 D-columns (ox), atomic per oc
    #pragma unroll
    for (int a = 0; a < 2; ++a) {
        float s0 = 0.f, s1 = 0.f, s2 = 0.f, s3 = 0.f;
        #pragma unroll
        for (int nf = 0; nf < 4; ++nf) {
            s0 += fmaxf(acc[a][nf][0], 0.f);
            s1 += fmaxf(acc[a][nf][1], 0.f);
            s2 += fmaxf(acc[a][nf][2], 0.f);
            s3 += fmaxf(acc[a][nf][3], 0.f);
        }
        #pragma unroll
        for (int off = 1; off < 16; off <<= 1) {
            s0 += __shfl_xor(s0, off);
            s1 += __shfl_xor(s1, off);
            s2 += __shfl_xor(s2, off);
            s3 += __shfl_xor(s3, off);
        }
        if (col == 0) {
            int ocb = wv * 32 + a * 16 + kq * 4;
            atomicAdd(&gsum[b * 128 + ocb + 0], s0);
            atomicAdd(&gsum[b * 128 + ocb + 1], s1);
            atomicAdd(&gsum[b * 128 + ocb + 2], s2);
            atomicAdd(&gsum[b * 128 + ocb + 3], s3);
        }
    }
}

// ---------------- final FC: mean = gsum/3136 ; [B,128] @ [128,10] + b
__global__ void fc_kernel(const float* __restrict__ gsum, const float* __restrict__ fcw,
                          const float* __restrict__ fcb, float* __restrict__ out) {
    int gid = blockIdx.x * blockDim.x + threadIdx.x;
    if (gid >= BB * NCLS) return;
    int cls = gid % NCLS, b = gid / NCLS;
    float s = 0.f;
    for (int c = 0; c < 128; ++c) s += gsum[b * 128 + c] * fcw[c * NCLS + cls];
    out[gid] = fcb[cls] + s * (1.f / 3136.f);
}

extern "C" void kernel_launch(void* const* d_in, const int* in_sizes, int n_in,
                              void* d_out, int out_size, void* d_ws, size_t ws_size,
                              hipStream_t stream) {
    const float* ff64  = (const float*)d_in[0];
    const float* ff224 = (const float*)d_in[1];
    const float* sw1   = (const float*)d_in[2];
    const float* sw2   = (const float*)d_in[3];
    const float* polw  = (const float*)d_in[4];
    const float* polb  = (const float*)d_in[5];
    const float* ew1   = (const float*)d_in[6];
    const float* ew2   = (const float*)d_in[7];
    const float* fcw   = (const float*)d_in[8];
    const float* fcb   = (const float*)d_in[9];
    float* out = (float*)d_out;

    float* ws = (float*)d_ws;
    float* skim_res = ws;                     // 196608 f
    float* h1 = skim_res + 196608;            // 524288 f
    float* h2 = h1 + 524288;                  // 262144 f
    int*   idx = (int*)(h2 + 262144);         // 80 int
    float* gsum = (float*)(idx + 80);         // 2048 f
    float* eval_in = gsum + 2048;             // 2408448 f
    unsigned short* g1cl = (unsigned short*)(eval_in + 2408448);  // 12845056 bf16
    unsigned short* wpk  = g1cl + 12845056;   // 73728 bf16
    unsigned short* wpk1 = wpk + 73728;       // 2048 bf16

    // skim branch (exact fp32 -> identical top-k selection)
    skim_resize_kernel<<<(196608 + 255) / 256, 256, 0, stream>>>(ff64, skim_res);
    conv_s2_relu_naive<<<(524288 + 255) / 256, 256, 0, stream>>>(
        skim_res, sw1, h1, BB, 3, 32, 64, 64, 32, 32);
    conv_s2_relu_naive<<<(262144 + 255) / 256, 256, 0, stream>>>(
        h1, sw2, h2, BB, 32, 64, 32, 32, 16, 16);
    policy_topk_kernel<<<BB, 64, 0, stream>>>(h2, polw, polb, idx);

    // pack conv1+conv2 weight fragments + zero gsum
    prep_w<<<(9 * 2 * 8 * 64 * 8 + 255) / 256, 256, 0, stream>>>(ew2, ew1, wpk, wpk1, gsum);

    // eval branch
    eval_resize_kernel<<<(2408448 + 255) / 256, 256, 0, stream>>>(ff224, idx, eval_in);
    conv1_mfma<<<dim3(7, 28, BB), 256, 0, stream>>>(eval_in, wpk1, g1cl);
    conv2_mfma<<<dim3(14, 4, BB), 256, 0, stream>>>(g1cl, wpk, gsum);
    fc_kernel<<<1, 256, 0, stream>>>(gsum, fcw, fcb, out);
}

// Round 6
// 174.865 us; speedup vs baseline: 6.9487x; 1.1276x over previous
//
#include <hip/hip_runtime.h>

#define BB 16
#define TT 30
#define NSEL 5
#define NCLS 10

typedef __attribute__((ext_vector_type(8))) short short8_t;
typedef __attribute__((ext_vector_type(4))) float f32x4;

__device__ inline unsigned short f2bf(float x) {
    unsigned int u = __float_as_uint(x);
    unsigned int r = u + 0x7FFFu + ((u >> 16) & 1u);
    return (unsigned short)(r >> 16);
}

// ---------------- skim resize: [B,T,3,64,64] -> [B,3,64,64]
__global__ void skim_resize_kernel(const float* __restrict__ ff64, float* __restrict__ out) {
    int gid = blockIdx.x * blockDim.x + threadIdx.x;
    if (gid >= BB * 3 * 64 * 64) return;
    int ox = gid & 63;
    int oy = (gid >> 6) & 63;
    int c  = (gid >> 12) % 3;
    int b  = gid >> 12; b /= 3;
    float sample = 30.f * (float)oy + 14.5f;
    int jlo = max(0, 30 * oy - 16);
    int jhi = min(TT * 64 - 1, 30 * oy + 45);
    float acc = 0.f, wsum = 0.f;
    for (int j = jlo; j <= jhi; ++j) {
        float w = fmaxf(0.f, 1.f - fabsf(sample - (float)j) * (1.f / 30.f));
        int t = j >> 6, y = j & 63;
        float v = ff64[(((b * TT + t) * 3 + c) << 12) + (y << 6) + ox];
        acc += w * v;
        wsum += w;
    }
    out[gid] = acc / wsum;
}

// ---------------- generic 3x3 stride-2 SAME conv + ReLU (small skim convs, exact fp32)
__global__ void conv_s2_relu_naive(const float* __restrict__ in, const float* __restrict__ w,
                                   float* __restrict__ out,
                                   int Bn, int Cin, int Cout, int Hin, int Win,
                                   int Hout, int Wout) {
    int gid = blockIdx.x * blockDim.x + threadIdx.x;
    int total = Bn * Cout * Hout * Wout;
    if (gid >= total) return;
    int ox = gid % Wout; int tmp = gid / Wout;
    int oy = tmp % Hout; tmp /= Hout;
    int oc = tmp % Cout; int b = tmp / Cout;
    float acc = 0.f;
    const float* wp = w + oc * Cin * 9;
    for (int ic = 0; ic < Cin; ++ic) {
        const float* ip = in + (size_t)(b * Cin + ic) * Hin * Win;
        #pragma unroll
        for (int ky = 0; ky < 3; ++ky) {
            int iy = 2 * oy + ky;
            if (iy >= Hin) continue;
            #pragma unroll
            for (int kx = 0; kx < 3; ++kx) {
                int ix = 2 * ox + kx;
                if (ix >= Win) continue;
                acc += wp[(ic * 3 + ky) * 3 + kx] * ip[iy * Win + ix];
            }
        }
    }
    out[gid] = fmaxf(acc, 0.f);
}

// ---------------- policy: mean(h2) -> relu -> @pol_w + pol_b -> top-5 idx sorted
__global__ void policy_topk_kernel(const float* __restrict__ h2, const float* __restrict__ pol_w,
                                   const float* __restrict__ pol_b, int* __restrict__ idx_out) {
    int b = blockIdx.x;
    int t = threadIdx.x; // 64 threads
    __shared__ float fea[64];
    __shared__ float logits[TT];
    const float* hp = h2 + (size_t)(b * 64 + t) * 256;
    float s = 0.f;
    for (int i = 0; i < 256; ++i) s += hp[i];
    fea[t] = fmaxf(s * (1.f / 256.f), 0.f);
    __syncthreads();
    if (t < TT) {
        float l = pol_b[t];
        for (int c = 0; c < 64; ++c) l += fea[c] * pol_w[c * TT + t];
        logits[t] = l;
    }
    __syncthreads();
    if (t == 0) {
        int sel[NSEL];
        bool used[TT];
        for (int i = 0; i < TT; ++i) used[i] = false;
        for (int k = 0; k < NSEL; ++k) {
            int best = 0; float bv = -1e30f; bool found = false;
            for (int i = 0; i < TT; ++i)
                if (!used[i] && (!found || logits[i] > bv)) { bv = logits[i]; best = i; found = true; }
            used[best] = true; sel[k] = best;
        }
        for (int a = 0; a < NSEL; ++a)
            for (int bb2 = a + 1; bb2 < NSEL; ++bb2)
                if (sel[bb2] < sel[a]) { int tmp = sel[a]; sel[a] = sel[bb2]; sel[bb2] = tmp; }
        for (int k = 0; k < NSEL; ++k) idx_out[b * NSEL + k] = sel[k];
    }
}

// ---------------- eval gather + resize (float4): FF224 gathered by idx -> [B,3,224,224]
__global__ void eval_resize4(const float* __restrict__ ff224, const int* __restrict__ idx,
                             float* __restrict__ out) {
    int gid = blockIdx.x * blockDim.x + threadIdx.x;
    int total = BB * 3 * 224 * 56;
    if (gid >= total) return;
    int xg = gid % 56; int tmp = gid / 56;
    int oy = tmp % 224; tmp /= 224;
    int c = tmp % 3; int b = tmp / 3;
    int ox0 = xg * 4;
    float sample = 5.f * (float)oy + 2.f;
    int jlo = max(0, 5 * oy - 3);
    int jhi = min(NSEL * 224 - 1, 5 * oy + 7);
    float ax = 0.f, ay = 0.f, az = 0.f, aw = 0.f, wsum = 0.f;
    for (int j = jlo; j <= jhi; ++j) {
        float w = fmaxf(0.f, 1.f - fabsf(sample - (float)j) * 0.2f);
        int s = j / 224, y = j % 224;
        int t = idx[b * NSEL + s];
        const float4 v = *(const float4*)&ff224[((size_t)((b * TT + t) * 3 + c) * 224 + y) * 224 + ox0];
        ax += w * v.x; ay += w * v.y; az += w * v.z; aw += w * v.w;
        wsum += w;
    }
    float inv = 1.f / wsum;
    float4 r; r.x = ax * inv; r.y = ay * inv; r.z = az * inv; r.w = aw * inv;
    *(float4*)&out[((size_t)((b * 3 + c) * 224 + oy)) * 224 + ox0] = r;
}

// ---------------- prep: pack conv2 + conv1 weight fragments, zero gsum
__global__ void prep_w(const float* __restrict__ w2, const float* __restrict__ w1,
                       unsigned short* __restrict__ wpk, unsigned short* __restrict__ wpk1,
                       float* __restrict__ gsum) {
    int i = blockIdx.x * blockDim.x + threadIdx.x;
    if (i < BB * 128) gsum[i] = 0.f;
    if (i < 4 * 64 * 8) {
        int j = i & 7;
        int lane = (i >> 3) & 63;
        int af = i >> 9;
        int oc = af * 16 + (lane & 15);
        int k = ((lane >> 4) << 3) + j;
        wpk1[i] = (k < 27) ? f2bf(w1[oc * 27 + k]) : (unsigned short)0;
    }
    if (i >= 9 * 2 * 8 * 64 * 8) return;
    int j = i & 7;
    int lane = (i >> 3) & 63;
    int af = (i >> 9) & 7;
    int h = (i >> 12) & 1;
    int tap = i >> 13;
    int oc = af * 16 + (lane & 15);
    int ic = h * 32 + ((lane >> 4) << 3) + j;
    int ky = tap / 3, kx = tap % 3;
    wpk[i] = f2bf(w2[((size_t)(oc * 64 + ic)) * 9 + ky * 3 + kx]);
}

// ---------------- eval conv1 via MFMA: [B,3,224,224] fp32 -> channels-last bf16 [B,112,112,64]
__global__ __launch_bounds__(256) void conv1_mfma(const float* __restrict__ in,
                                                  const unsigned short* __restrict__ wpk1,
                                                  unsigned short* __restrict__ outcl) {
    int oxT = blockIdx.x;            // 0..6
    int oyT = blockIdx.y;            // 0..27
    int b = blockIdx.z;
    int t = threadIdx.x;
    int w = t >> 6;                  // wave -> oy = oyT*4 + w
    int lane = t & 63;
    int col = lane & 15;
    int kq = lane >> 4;

    __shared__ float in_s[3][9][36];

    int iy0 = oyT * 8, ix0 = oxT * 32;
    const float* ib = in + (size_t)b * 3 * 224 * 224;
    for (int i = t; i < 3 * 9 * 36; i += 256) {
        int rx = i % 36; int tmp = i / 36;
        int ry = tmp % 9; int ic = tmp / 9;
        int iy = iy0 + ry, ix = ix0 + rx;
        float v = 0.f;
        if (iy < 224 && ix < 224 && rx < 34) v = ib[((size_t)ic * 224 + iy) * 224 + ix];
        in_s[ic][ry][rx] = v;
    }
    __syncthreads();

    short8_t a[4];
    #pragma unroll
    for (int af = 0; af < 4; ++af)
        a[af] = *(const short8_t*)&wpk1[((af << 6) + lane) << 3];

    unsigned int bw[4];
    #pragma unroll
    for (int jj = 0; jj < 4; ++jj) {
        unsigned int lo = 0, hi = 0;
        int k0 = (kq << 3) + jj * 2;
        {
            int k = k0;
            if (k < 27) {
                int ic = k / 9, r9 = k - ic * 9;
                int ky = r9 / 3, kx = r9 - ky * 3;
                lo = f2bf(in_s[ic][2 * w + ky][2 * col + kx]);
            }
        }
        {
            int k = k0 + 1;
            if (k < 27) {
                int ic = k / 9, r9 = k - ic * 9;
                int ky = r9 / 3, kx = r9 - ky * 3;
                hi = f2bf(in_s[ic][2 * w + ky][2 * col + kx]);
            }
        }
        bw[jj] = lo | (hi << 16);
    }
    short8_t bv;
    {
        unsigned int* bvp = (unsigned int*)&bv;
        bvp[0] = bw[0]; bvp[1] = bw[1]; bvp[2] = bw[2]; bvp[3] = bw[3];
    }

    f32x4 acc[4];
    #pragma unroll
    for (int af = 0; af < 4; ++af) {
        acc[af] = (f32x4){0.f, 0.f, 0.f, 0.f};
        acc[af] = __builtin_amdgcn_mfma_f32_16x16x32_bf16(a[af], bv, acc[af], 0, 0, 0);
    }

    int oy = oyT * 4 + w;
    int ox = oxT * 16 + col;
    size_t pxb = ((size_t)((b * 112 + oy) * 112 + ox)) << 6;
    #pragma unroll
    for (int af = 0; af < 4; ++af) {
        unsigned int p0 = f2bf(fmaxf(acc[af][0], 0.f)) | ((unsigned int)f2bf(fmaxf(acc[af][1], 0.f)) << 16);
        unsigned int p1 = f2bf(fmaxf(acc[af][2], 0.f)) | ((unsigned int)f2bf(fmaxf(acc[af][3], 0.f)) << 16);
        uint2 pk; pk.x = p0; pk.y = p1;
        *(uint2*)&outcl[pxb + (af << 4) + (kq << 2)] = pk;
    }
}

// ---------------- eval conv2 via MFMA + LDS input, fused relu+mean -> gsum[B,128]
// tap loop NOT unrolled: keeps live VGPRs ~80 (full unroll spilled to scratch)
__global__ __launch_bounds__(256) void conv2_mfma(const unsigned short* __restrict__ g1cl,
                                                  const unsigned short* __restrict__ wpk,
                                                  float* __restrict__ gsum) {
    int oyT = blockIdx.x;            // 0..13 -> oy0 = oyT*4
    int oxT = blockIdx.y;            // 0..3  -> ox0 = oxT*16
    int b = blockIdx.z;
    int t = threadIdx.x;
    int wv = t >> 6;                 // 0..3 -> oc base wv*32
    int lane = t & 63;
    int col = lane & 15;
    int kq = lane >> 4;

    __shared__ unsigned short tile[9 * 34 * 64];

    int iy0 = oyT * 8, ix0 = oxT * 32;
    for (int u = t; u < 9 * 34 * 8; u += 256) {
        int cg = u & 7;
        int r = u >> 3;
        int rx = r % 34, ry = r / 34;
        int iy = iy0 + ry, ix = ix0 + rx;
        uint4 v = {0, 0, 0, 0};
        if (iy < 112 && ix < 112)
            v = *(const uint4*)&g1cl[(((size_t)((b * 112 + iy) * 112 + ix)) << 6) + (cg << 3)];
        int byte = ((r << 6) + (cg << 3)) << 1;
        byte ^= ((r >> 1) & 7) << 4;
        *(uint4*)((char*)tile + byte) = v;
    }
    __syncthreads();

    f32x4 acc[2][4];
    #pragma unroll
    for (int a = 0; a < 2; ++a)
        #pragma unroll
        for (int n = 0; n < 4; ++n)
            acc[a][n] = (f32x4){0.f, 0.f, 0.f, 0.f};

    #pragma unroll 1
    for (int tap = 0; tap < 9; ++tap) {
        const int ky = tap / 3;
        const int kx = tap - ky * 3;
        const int rxl = 2 * col + kx;
        #pragma unroll
        for (int h = 0; h < 2; ++h) {
            const unsigned short* wp = wpk + ((size_t)(((tap * 2 + h) * 8) + (wv << 1)) * 64 + lane) * 8;
            short8_t a0 = *(const short8_t*)wp;
            short8_t a1 = *(const short8_t*)(wp + 512);
            const int e = (h << 5) + (kq << 3);
            #pragma unroll
            for (int nf = 0; nf < 4; ++nf) {
                int r = (2 * nf + ky) * 34 + rxl;
                int byte = (((r << 6) + e) << 1) ^ (((r >> 1) & 7) << 4);
                short8_t bv = *(const short8_t*)((const char*)tile + byte);
                acc[0][nf] = __builtin_amdgcn_mfma_f32_16x16x32_bf16(a0, bv, acc[0][nf], 0, 0, 0);
                acc[1][nf] = __builtin_amdgcn_mfma_f32_16x16x32_bf16(a1, bv, acc[1][nf], 0, 0, 0);
            }
        }
    }

    #pragma unroll
    for (int a = 0; a < 2; ++a) {
        float s0 = 0.f, s1 = 0.f, s2 = 0.f, s3 = 0.f;
        #pragma unroll
        for (int nf = 0; nf < 4; ++nf) {
            s0 += fmaxf(acc[a][nf][0], 0.f);
            s1 += fmaxf(acc[a][nf][1], 0.f);
            s2 += fmaxf(acc[a][nf][2], 0.f);
            s3 += fmaxf(acc[a][nf][3], 0.f);
        }
        #pragma unroll
        for (int off = 1; off < 16; off <<= 1) {
            s0 += __shfl_xor(s0, off);
            s1 += __shfl_xor(s1, off);
            s2 += __shfl_xor(s2, off);
            s3 += __shfl_xor(s3, off);
        }
        if (col == 0) {
            int ocb = wv * 32 + a * 16 + kq * 4;
            atomicAdd(&gsum[b * 128 + ocb + 0], s0);
            atomicAdd(&gsum[b * 128 + ocb + 1], s1);
            atomicAdd(&gsum[b * 128 + ocb + 2], s2);
            atomicAdd(&gsum[b * 128 + ocb + 3], s3);
        }
    }
}

// ---------------- final FC: mean = gsum/3136 ; [B,128] @ [128,10] + b
__global__ void fc_kernel(const float* __restrict__ gsum, const float* __restrict__ fcw,
                          const float* __restrict__ fcb, float* __restrict__ out) {
    int gid = blockIdx.x * blockDim.x + threadIdx.x;
    if (gid >= BB * NCLS) return;
    int cls = gid % NCLS, b = gid / NCLS;
    float s = 0.f;
    for (int c = 0; c < 128; ++c) s += gsum[b * 128 + c] * fcw[c * NCLS + cls];
    out[gid] = fcb[cls] + s * (1.f / 3136.f);
}

extern "C" void kernel_launch(void* const* d_in, const int* in_sizes, int n_in,
                              void* d_out, int out_size, void* d_ws, size_t ws_size,
                              hipStream_t stream) {
    const float* ff64  = (const float*)d_in[0];
    const float* ff224 = (const float*)d_in[1];
    const float* sw1   = (const float*)d_in[2];
    const float* sw2   = (const float*)d_in[3];
    const float* polw  = (const float*)d_in[4];
    const float* polb  = (const float*)d_in[5];
    const float* ew1   = (const float*)d_in[6];
    const float* ew2   = (const float*)d_in[7];
    const float* fcw   = (const float*)d_in[8];
    const float* fcb   = (const float*)d_in[9];
    float* out = (float*)d_out;

    float* ws = (float*)d_ws;
    float* skim_res = ws;                     // 196608 f
    float* h1 = skim_res + 196608;            // 524288 f
    float* h2 = h1 + 524288;                  // 262144 f
    int*   idx = (int*)(h2 + 262144);         // 80 int
    float* gsum = (float*)(idx + 80);         // 2048 f
    float* eval_in = gsum + 2048;             // 2408448 f
    unsigned short* g1cl = (unsigned short*)(eval_in + 2408448);  // 12845056 bf16
    unsigned short* wpk  = g1cl + 12845056;   // 73728 bf16
    unsigned short* wpk1 = wpk + 73728;       // 2048 bf16

    // skim branch (exact fp32 -> identical top-k selection)
    skim_resize_kernel<<<(196608 + 255) / 256, 256, 0, stream>>>(ff64, skim_res);
    conv_s2_relu_naive<<<(524288 + 255) / 256, 256, 0, stream>>>(
        skim_res, sw1, h1, BB, 3, 32, 64, 64, 32, 32);
    conv_s2_relu_naive<<<(262144 + 255) / 256, 256, 0, stream>>>(
        h1, sw2, h2, BB, 32, 64, 32, 32, 16, 16);
    policy_topk_kernel<<<BB, 64, 0, stream>>>(h2, polw, polb, idx);

    // pack conv1+conv2 weight fragments + zero gsum
    prep_w<<<(9 * 2 * 8 * 64 * 8 + 255) / 256, 256, 0, stream>>>(ew2, ew1, wpk, wpk1, gsum);

    // eval branch
    eval_resize4<<<(BB * 3 * 224 * 56 + 255) / 256, 256, 0, stream>>>(ff224, idx, eval_in);
    conv1_mfma<<<dim3(7, 28, BB), 256, 0, stream>>>(eval_in, wpk1, g1cl);
    conv2_mfma<<<dim3(14, 4, BB), 256, 0, stream>>>(g1cl, wpk, gsum);
    fc_kernel<<<1, 256, 0, stream>>>(gsum, fcw, fcb, out);
}

// Round 7
// 126.599 us; speedup vs baseline: 9.5979x; 1.3813x over previous
//
#include <hip/hip_runtime.h>

#define BB 16
#define TT 30
#define NSEL 5
#define NCLS 10

typedef __attribute__((ext_vector_type(8))) short short8_t;
typedef __attribute__((ext_vector_type(4))) float f32x4;

__device__ inline unsigned short f2bf(float x) {
    unsigned int u = __float_as_uint(x);
    unsigned int r = u + 0x7FFFu + ((u >> 16) & 1u);
    return (unsigned short)(r >> 16);
}

// ---------------- skim resize: [B,T,3,64,64] -> [B,3,64,64]
__global__ void skim_resize_kernel(const float* __restrict__ ff64, float* __restrict__ out) {
    int gid = blockIdx.x * blockDim.x + threadIdx.x;
    if (gid >= BB * 3 * 64 * 64) return;
    int ox = gid & 63;
    int oy = (gid >> 6) & 63;
    int c  = (gid >> 12) % 3;
    int b  = gid >> 12; b /= 3;
    float sample = 30.f * (float)oy + 14.5f;
    int jlo = max(0, 30 * oy - 16);
    int jhi = min(TT * 64 - 1, 30 * oy + 45);
    float acc = 0.f, wsum = 0.f;
    for (int j = jlo; j <= jhi; ++j) {
        float w = fmaxf(0.f, 1.f - fabsf(sample - (float)j) * (1.f / 30.f));
        int t = j >> 6, y = j & 63;
        float v = ff64[(((b * TT + t) * 3 + c) << 12) + (y << 6) + ox];
        acc += w * v;
        wsum += w;
    }
    out[gid] = acc / wsum;
}

// ---------------- skim conv1 tiled fp32 (exact): [16,3,64,64] -> [16,32,32,32]
// grid 512 = (b,oy); block 256 = 32 oc x 8 oxg (4 px each)
__global__ __launch_bounds__(256) void sconv1_t(const float* __restrict__ in,
                                                const float* __restrict__ w,
                                                float* __restrict__ h1) {
    int oy = blockIdx.x & 31;
    int b  = blockIdx.x >> 5;
    int t = threadIdx.x;
    int oc = t & 31;
    int oxg = t >> 5;

    __shared__ float in_s[3][3][64];
    __shared__ float w_s[27][32];

    int iy0 = oy * 2;
    for (int u = t; u < 576; u += 256) {
        int ix = u & 63;
        int ry = (u >> 6) % 3;
        int ic = u / 192;
        int iy = iy0 + ry;
        in_s[ic][ry][ix] = (iy < 64) ? in[((b * 3 + ic) * 64 + iy) * 64 + ix] : 0.f;
    }
    for (int u = t; u < 864; u += 256) {
        int oc2 = u & 31;
        int k = u >> 5;
        w_s[k][oc2] = w[oc2 * 27 + k];
    }
    __syncthreads();

    float acc[4] = {0.f, 0.f, 0.f, 0.f};
    #pragma unroll
    for (int ic = 0; ic < 3; ++ic) {
        #pragma unroll
        for (int ky = 0; ky < 3; ++ky) {
            float xv[9];
            #pragma unroll
            for (int i = 0; i < 9; ++i) {
                int ix = oxg * 8 + i;
                xv[i] = (ix < 64) ? in_s[ic][ky][ix] : 0.f;
            }
            #pragma unroll
            for (int kx = 0; kx < 3; ++kx) {
                float wv = w_s[ic * 9 + ky * 3 + kx][oc];
                #pragma unroll
                for (int p = 0; p < 4; ++p) acc[p] += wv * xv[2 * p + kx];
            }
        }
    }
    float* op = &h1[((b * 32 + oc) * 32 + oy) * 32 + oxg * 4];
    #pragma unroll
    for (int p = 0; p < 4; ++p) op[p] = fmaxf(acc[p], 0.f);
}

// ---------------- skim conv2 tiled fp32 (exact) fused relu+mean: [16,32,32,32] -> gsum2[16,64]
// grid (16 oy, 2 ocg, 16 b); block 256 = 32 oc x 8 oxg (2 px each)
__global__ __launch_bounds__(256) void sconv2_t(const float* __restrict__ h1,
                                                const float* __restrict__ w,
                                                float* __restrict__ gsum2) {
    int oy = blockIdx.x;
    int ocg = blockIdx.y;
    int b = blockIdx.z;
    int t = threadIdx.x;
    int oc = t & 31;
    int oxg = t >> 5;

    __shared__ float in_s[32][3][32];
    __shared__ float w_s[288 * 32];   // [R=ic*9+k][oc ^ (R&31)]

    int iy0 = oy * 2;
    for (int u = t; u < 32 * 3 * 32; u += 256) {
        int ix = u & 31;
        int ry = (u >> 5) % 3;
        int ic = u / 96;
        int iy = iy0 + ry;
        in_s[ic][ry][ix] = (iy < 32) ? h1[((b * 32 + ic) * 32 + iy) * 32 + ix] : 0.f;
    }
    for (int u = t; u < 9216; u += 256) {
        int ocl = u / 288;
        int rem = u - ocl * 288;
        w_s[rem * 32 + (ocl ^ (rem & 31))] = w[(ocg * 32 + ocl) * 288 + rem];
    }
    __syncthreads();

    float acc0 = 0.f, acc1 = 0.f;
    for (int ic = 0; ic < 32; ++ic) {
        #pragma unroll
        for (int ky = 0; ky < 3; ++ky) {
            float xv[5];
            #pragma unroll
            for (int i = 0; i < 5; ++i) {
                int ix = oxg * 4 + i;
                xv[i] = (ix < 32) ? in_s[ic][ky][ix] : 0.f;
            }
            #pragma unroll
            for (int kx = 0; kx < 3; ++kx) {
                int R = ic * 9 + ky * 3 + kx;
                float wv = w_s[R * 32 + (oc ^ (R & 31))];
                acc0 += wv * xv[kx];
                acc1 += wv * xv[2 + kx];
            }
        }
    }
    float ps = fmaxf(acc0, 0.f) + fmaxf(acc1, 0.f);
    ps += __shfl_xor(ps, 32);
    if ((t & 32) == 0) atomicAdd(&gsum2[b * 64 + ocg * 32 + oc], ps);
}

// ---------------- policy: fea = gsum2/256 -> relu -> @pol_w + pol_b -> top-5 idx sorted
__global__ void policy_topk_kernel(const float* __restrict__ gsum2, const float* __restrict__ pol_w,
                                   const float* __restrict__ pol_b, int* __restrict__ idx_out) {
    int b = blockIdx.x;
    int t = threadIdx.x; // 64 threads
    __shared__ float fea[64];
    __shared__ float logits[TT];
    fea[t] = fmaxf(gsum2[b * 64 + t] * (1.f / 256.f), 0.f);
    __syncthreads();
    if (t < TT) {
        float l = pol_b[t];
        for (int c = 0; c < 64; ++c) l += fea[c] * pol_w[c * TT + t];
        logits[t] = l;
    }
    __syncthreads();
    if (t == 0) {
        int sel[NSEL];
        bool used[TT];
        for (int i = 0; i < TT; ++i) used[i] = false;
        for (int k = 0; k < NSEL; ++k) {
            int best = 0; float bv = -1e30f; bool found = false;
            for (int i = 0; i < TT; ++i)
                if (!used[i] && (!found || logits[i] > bv)) { bv = logits[i]; best = i; found = true; }
            used[best] = true; sel[k] = best;
        }
        for (int a = 0; a < NSEL; ++a)
            for (int bb2 = a + 1; bb2 < NSEL; ++bb2)
                if (sel[bb2] < sel[a]) { int tmp = sel[a]; sel[a] = sel[bb2]; sel[bb2] = tmp; }
        for (int k = 0; k < NSEL; ++k) idx_out[b * NSEL + k] = sel[k];
    }
}

// ---------------- eval gather + resize (float4): FF224 gathered by idx -> [B,3,224,224]
__global__ void eval_resize4(const float* __restrict__ ff224, const int* __restrict__ idx,
                             float* __restrict__ out) {
    int gid = blockIdx.x * blockDim.x + threadIdx.x;
    int total = BB * 3 * 224 * 56;
    if (gid >= total) return;
    int xg = gid % 56; int tmp = gid / 56;
    int oy = tmp % 224; tmp /= 224;
    int c = tmp % 3; int b = tmp / 3;
    int ox0 = xg * 4;
    float sample = 5.f * (float)oy + 2.f;
    int jlo = max(0, 5 * oy - 3);
    int jhi = min(NSEL * 224 - 1, 5 * oy + 7);
    float ax = 0.f, ay = 0.f, az = 0.f, aw = 0.f, wsum = 0.f;
    for (int j = jlo; j <= jhi; ++j) {
        float w = fmaxf(0.f, 1.f - fabsf(sample - (float)j) * 0.2f);
        int s = j / 224, y = j % 224;
        int t = idx[b * NSEL + s];
        const float4 v = *(const float4*)&ff224[((size_t)((b * TT + t) * 3 + c) * 224 + y) * 224 + ox0];
        ax += w * v.x; ay += w * v.y; az += w * v.z; aw += w * v.w;
        wsum += w;
    }
    float inv = 1.f / wsum;
    float4 r; r.x = ax * inv; r.y = ay * inv; r.z = az * inv; r.w = aw * inv;
    *(float4*)&out[((size_t)((b * 3 + c) * 224 + oy)) * 224 + ox0] = r;
}

// ---------------- prep: pack conv2 + conv1 weight fragments, zero gsum/gsum2
__global__ void prep_w(const float* __restrict__ w2, const float* __restrict__ w1,
                       unsigned short* __restrict__ wpk, unsigned short* __restrict__ wpk1,
                       float* __restrict__ gsum, float* __restrict__ gsum2) {
    int i = blockIdx.x * blockDim.x + threadIdx.x;
    if (i < BB * 128) gsum[i] = 0.f;
    if (i < BB * 64) gsum2[i] = 0.f;
    if (i < 4 * 64 * 8) {
        int j = i & 7;
        int lane = (i >> 3) & 63;
        int af = i >> 9;
        int oc = af * 16 + (lane & 15);
        int k = ((lane >> 4) << 3) + j;
        wpk1[i] = (k < 27) ? f2bf(w1[oc * 27 + k]) : (unsigned short)0;
    }
    if (i >= 9 * 2 * 8 * 64 * 8) return;
    int j = i & 7;
    int lane = (i >> 3) & 63;
    int af = (i >> 9) & 7;
    int h = (i >> 12) & 1;
    int tap = i >> 13;
    int oc = af * 16 + (lane & 15);
    int ic = h * 32 + ((lane >> 4) << 3) + j;
    int ky = tap / 3, kx = tap % 3;
    wpk[i] = f2bf(w2[((size_t)(oc * 64 + ic)) * 9 + ky * 3 + kx]);
}

// ---------------- eval conv1 via MFMA: [B,3,224,224] fp32 -> channels-last bf16 [B,112,112,64]
__global__ __launch_bounds__(256) void conv1_mfma(const float* __restrict__ in,
                                                  const unsigned short* __restrict__ wpk1,
                                                  unsigned short* __restrict__ outcl) {
    int oxT = blockIdx.x;            // 0..6
    int oyT = blockIdx.y;            // 0..27
    int b = blockIdx.z;
    int t = threadIdx.x;
    int w = t >> 6;                  // wave -> oy = oyT*4 + w
    int lane = t & 63;
    int col = lane & 15;
    int kq = lane >> 4;

    __shared__ float in_s[3][9][36];

    int iy0 = oyT * 8, ix0 = oxT * 32;
    const float* ib = in + (size_t)b * 3 * 224 * 224;
    for (int i = t; i < 3 * 9 * 36; i += 256) {
        int rx = i % 36; int tmp = i / 36;
        int ry = tmp % 9; int ic = tmp / 9;
        int iy = iy0 + ry, ix = ix0 + rx;
        float v = 0.f;
        if (iy < 224 && ix < 224 && rx < 34) v = ib[((size_t)ic * 224 + iy) * 224 + ix];
        in_s[ic][ry][rx] = v;
    }
    __syncthreads();

    short8_t a[4];
    #pragma unroll
    for (int af = 0; af < 4; ++af)
        a[af] = *(const short8_t*)&wpk1[((af << 6) + lane) << 3];

    unsigned int bw[4];
    #pragma unroll
    for (int jj = 0; jj < 4; ++jj) {
        unsigned int lo = 0, hi = 0;
        int k0 = (kq << 3) + jj * 2;
        {
            int k = k0;
            if (k < 27) {
                int ic = k / 9, r9 = k - ic * 9;
                int ky = r9 / 3, kx = r9 - ky * 3;
                lo = f2bf(in_s[ic][2 * w + ky][2 * col + kx]);
            }
        }
        {
            int k = k0 + 1;
            if (k < 27) {
                int ic = k / 9, r9 = k - ic * 9;
                int ky = r9 / 3, kx = r9 - ky * 3;
                hi = f2bf(in_s[ic][2 * w + ky][2 * col + kx]);
            }
        }
        bw[jj] = lo | (hi << 16);
    }
    short8_t bv;
    {
        unsigned int* bvp = (unsigned int*)&bv;
        bvp[0] = bw[0]; bvp[1] = bw[1]; bvp[2] = bw[2]; bvp[3] = bw[3];
    }

    f32x4 acc[4];
    #pragma unroll
    for (int af = 0; af < 4; ++af) {
        acc[af] = (f32x4){0.f, 0.f, 0.f, 0.f};
        acc[af] = __builtin_amdgcn_mfma_f32_16x16x32_bf16(a[af], bv, acc[af], 0, 0, 0);
    }

    int oy = oyT * 4 + w;
    int ox = oxT * 16 + col;
    size_t pxb = ((size_t)((b * 112 + oy) * 112 + ox)) << 6;
    #pragma unroll
    for (int af = 0; af < 4; ++af) {
        unsigned int p0 = f2bf(fmaxf(acc[af][0], 0.f)) | ((unsigned int)f2bf(fmaxf(acc[af][1], 0.f)) << 16);
        unsigned int p1 = f2bf(fmaxf(acc[af][2], 0.f)) | ((unsigned int)f2bf(fmaxf(acc[af][3], 0.f)) << 16);
        uint2 pk; pk.x = p0; pk.y = p1;
        *(uint2*)&outcl[pxb + (af << 4) + (kq << 2)] = pk;
    }
}

// ---------------- eval conv2 via MFMA + LDS input, fused relu+mean -> gsum[B,128]
// tap loop NOT unrolled: keeps live VGPRs low (full unroll spilled to scratch)
__global__ __launch_bounds__(256) void conv2_mfma(const unsigned short* __restrict__ g1cl,
                                                  const unsigned short* __restrict__ wpk,
                                                  float* __restrict__ gsum) {
    int oyT = blockIdx.x;            // 0..13 -> oy0 = oyT*4
    int oxT = blockIdx.y;            // 0..3  -> ox0 = oxT*16
    int b = blockIdx.z;
    int t = threadIdx.x;
    int wv = t >> 6;                 // 0..3 -> oc base wv*32
    int lane = t & 63;
    int col = lane & 15;
    int kq = lane >> 4;

    __shared__ unsigned short tile[9 * 34 * 64];

    int iy0 = oyT * 8, ix0 = oxT * 32;
    for (int u = t; u < 9 * 34 * 8; u += 256) {
        int cg = u & 7;
        int r = u >> 3;
        int rx = r % 34, ry = r / 34;
        int iy = iy0 + ry, ix = ix0 + rx;
        uint4 v = {0, 0, 0, 0};
        if (iy < 112 && ix < 112)
            v = *(const uint4*)&g1cl[(((size_t)((b * 112 + iy) * 112 + ix)) << 6) + (cg << 3)];
        int byte = ((r << 6) + (cg << 3)) << 1;
        byte ^= ((r >> 1) & 7) << 4;
        *(uint4*)((char*)tile + byte) = v;
    }
    __syncthreads();

    f32x4 acc[2][4];
    #pragma unroll
    for (int a = 0; a < 2; ++a)
        #pragma unroll
        for (int n = 0; n < 4; ++n)
            acc[a][n] = (f32x4){0.f, 0.f, 0.f, 0.f};

    #pragma unroll 1
    for (int tap = 0; tap < 9; ++tap) {
        const int ky = tap / 3;
        const int kx = tap - ky * 3;
        const int rxl = 2 * col + kx;
        #pragma unroll
        for (int h = 0; h < 2; ++h) {
            const unsigned short* wp = wpk + ((size_t)(((tap * 2 + h) * 8) + (wv << 1)) * 64 + lane) * 8;
            short8_t a0 = *(const short8_t*)wp;
            short8_t a1 = *(const short8_t*)(wp + 512);
            const int e = (h << 5) + (kq << 3);
            #pragma unroll
            for (int nf = 0; nf < 4; ++nf) {
                int r = (2 * nf + ky) * 34 + rxl;
                int byte = (((r << 6) + e) << 1) ^ (((r >> 1) & 7) << 4);
                short8_t bv = *(const short8_t*)((const char*)tile + byte);
                acc[0][nf] = __builtin_amdgcn_mfma_f32_16x16x32_bf16(a0, bv, acc[0][nf], 0, 0, 0);
                acc[1][nf] = __builtin_amdgcn_mfma_f32_16x16x32_bf16(a1, bv, acc[1][nf], 0, 0, 0);
            }
        }
    }

    #pragma unroll
    for (int a = 0; a < 2; ++a) {
        float s0 = 0.f, s1 = 0.f, s2 = 0.f, s3 = 0.f;
        #pragma unroll
        for (int nf = 0; nf < 4; ++nf) {
            s0 += fmaxf(acc[a][nf][0], 0.f);
            s1 += fmaxf(acc[a][nf][1], 0.f);
            s2 += fmaxf(acc[a][nf][2], 0.f);
            s3 += fmaxf(acc[a][nf][3], 0.f);
        }
        #pragma unroll
        for (int off = 1; off < 16; off <<= 1) {
            s0 += __shfl_xor(s0, off);
            s1 += __shfl_xor(s1, off);
            s2 += __shfl_xor(s2, off);
            s3 += __shfl_xor(s3, off);
        }
        if (col == 0) {
            int ocb = wv * 32 + a * 16 + kq * 4;
            atomicAdd(&gsum[b * 128 + ocb + 0], s0);
            atomicAdd(&gsum[b * 128 + ocb + 1], s1);
            atomicAdd(&gsum[b * 128 + ocb + 2], s2);
            atomicAdd(&gsum[b * 128 + ocb + 3], s3);
        }
    }
}

// ---------------- final FC: mean = gsum/3136 ; [B,128] @ [128,10] + b
__global__ void fc_kernel(const float* __restrict__ gsum, const float* __restrict__ fcw,
                          const float* __restrict__ fcb, float* __restrict__ out) {
    int gid = blockIdx.x * blockDim.x + threadIdx.x;
    if (gid >= BB * NCLS) return;
    int cls = gid % NCLS, b = gid / NCLS;
    float s = 0.f;
    for (int c = 0; c < 128; ++c) s += gsum[b * 128 + c] * fcw[c * NCLS + cls];
    out[gid] = fcb[cls] + s * (1.f / 3136.f);
}

extern "C" void kernel_launch(void* const* d_in, const int* in_sizes, int n_in,
                              void* d_out, int out_size, void* d_ws, size_t ws_size,
                              hipStream_t stream) {
    const float* ff64  = (const float*)d_in[0];
    const float* ff224 = (const float*)d_in[1];
    const float* sw1   = (const float*)d_in[2];
    const float* sw2   = (const float*)d_in[3];
    const float* polw  = (const float*)d_in[4];
    const float* polb  = (const float*)d_in[5];
    const float* ew1   = (const float*)d_in[6];
    const float* ew2   = (const float*)d_in[7];
    const float* fcw   = (const float*)d_in[8];
    const float* fcb   = (const float*)d_in[9];
    float* out = (float*)d_out;

    float* ws = (float*)d_ws;
    float* skim_res = ws;                      // 196608 f
    float* h1 = skim_res + 196608;             // 524288 f
    float* gsum2 = h1 + 524288;                // 1024 f
    float* gsum = gsum2 + 1024;                // 2048 f
    int*   idx = (int*)(gsum + 2048);          // 96 int (80 used)
    float* eval_in = (float*)(idx + 96);       // 2408448 f
    unsigned short* g1cl = (unsigned short*)(eval_in + 2408448);  // 12845056 bf16
    unsigned short* wpk  = g1cl + 12845056;    // 73728 bf16
    unsigned short* wpk1 = wpk + 73728;        // 2048 bf16

    // prep (independent): pack eval weight fragments + zero accumulators
    prep_w<<<(9 * 2 * 8 * 64 * 8 + 255) / 256, 256, 0, stream>>>(ew2, ew1, wpk, wpk1, gsum, gsum2);

    // skim branch (exact fp32 -> identical top-k selection)
    skim_resize_kernel<<<(196608 + 255) / 256, 256, 0, stream>>>(ff64, skim_res);
    sconv1_t<<<512, 256, 0, stream>>>(skim_res, sw1, h1);
    sconv2_t<<<dim3(16, 2, BB), 256, 0, stream>>>(h1, sw2, gsum2);
    policy_topk_kernel<<<BB, 64, 0, stream>>>(gsum2, polw, polb, idx);

    // eval branch
    eval_resize4<<<(BB * 3 * 224 * 56 + 255) / 256, 256, 0, stream>>>(ff224, idx, eval_in);
    conv1_mfma<<<dim3(7, 28, BB), 256, 0, stream>>>(eval_in, wpk1, g1cl);
    conv2_mfma<<<dim3(14, 4, BB), 256, 0, stream>>>(g1cl, wpk, gsum);
    fc_kernel<<<1, 256, 0, stream>>>(gsum, fcw, fcb, out);
}